// Round 7
// baseline (3641.264 us; speedup 1.0000x reference)
//
#include <hip/hip_runtime.h>

// StackedFlow v6b: fit-in-128-VGPR redesign (v6 + compile fix: braced init inside MF macro).
// r3/r4/r5: every allocator lever (launch_bounds(512,1), waves_per_eu(2,2), static LDS)
// left VGPR_Count=128 with ~82MB/dispatch spill stores. v6 stops fighting: 16 waves
// (1024 thr), n-slice 16/wave -> W1 slice 32 VGPR, y/ka/kc 8 each, persistent ~64,
// peak ~116 < 128. At 1024 thr + 155KB LDS, achievable occupancy (4 waves/EU) equals
// the compiler's default budget target -> no spill by construction.
// Also: h1/ys swizzle upgraded (m&7)->(m&15)<<4 (full 16-slot spread on G2/G3 reads).

#define LNUM   4
#define NSTEP  8
#define EPSV   1e-3f

typedef __attribute__((ext_vector_type(8))) short  short8;
typedef __attribute__((ext_vector_type(4))) float  floatx4;

#define MF(a, b, c) __builtin_amdgcn_mfma_f32_16x16x32_bf16((a), (b), (c), 0, 0, 0)

// d_ws layout (bf16 element offsets), per-GEMM fragment arrays [layer][nt*KS+ks][lane][8]
#define OW0_OFF 0        // ode W0 rows 1..64  (64 x 256)
#define OW1_OFF 65536    // ode W1            (256 x 256)
#define OW2_OFF 327680   // ode W2            (256 x 64)
#define NW0_OFF 393216   // nvp W0            (32 x 256)
#define NW1_OFF 425984   // nvp W1            (256 x 256)
#define NW2_OFF 688128   // nvp W2            (256 x 64)
#define WS_ELEMS 753664

// LDS byte offsets
#define H1_OFF   0        // 64K bf16 [128][256] RS=512 swz((m&15)<<4)
#define YS_OFF   65536    // 32K fp32 [128][64]  RS=256 swz((m&15)<<4)
#define YIN_OFF  98304    // 16K bf16 [128][64]  RS=128 swz((m&7)<<4)   (x0 in NVP phase)
#define SHF_OFF  114688   // 8K  bf16 [128][32]  RS=64  swz((m&3)<<4)
#define W2B_OFF  122880   // 32K short8[2048] W2 fragments (NVP then ODE)
#define PARS_OFF 155648   // 3328B: b0 | b1(+256) | b2(+512) | w0row0(+576)
#define LDS_SIZE 158976

__device__ __forceinline__ unsigned short f2bfu(float f) {
  unsigned int u = __float_as_uint(f);
  return (unsigned short)((u + 0x7FFFu + ((u >> 16) & 1u)) >> 16);  // RNE
}

__device__ __forceinline__ unsigned long long pack4bf(float a, float b, float c, float d) {
  return (unsigned long long)f2bfu(a)
       | ((unsigned long long)f2bfu(b) << 16)
       | ((unsigned long long)f2bfu(c) << 32)
       | ((unsigned long long)f2bfu(d) << 48);
}

__device__ __forceinline__ float bfu2f(unsigned short u) {
  return __uint_as_float((unsigned int)u << 16);
}

__device__ __forceinline__ float tanh_fast(float x) {
  float e = __expf(2.0f * x);
  return 1.0f - 2.0f * __builtin_amdgcn_rcpf(e + 1.0f);
}

// ---------------- weight prep: fp32 [K][N] -> bf16 A-fragment order (unchanged) ----------------
__global__ void prep_kernel(const float* __restrict__ odeW0, const float* __restrict__ odeW1,
                            const float* __restrict__ odeW2, const float* __restrict__ nvpW0,
                            const float* __restrict__ nvpW1, const float* __restrict__ nvpW2,
                            unsigned short* __restrict__ ws) {
  int idx = blockIdx.x * blockDim.x + threadIdx.x;
  if (idx >= WS_ELEMS) return;
  const float* W; int base, K, N, lstride, skip;
  int f = idx;
  if (f < OW1_OFF)      { W = odeW0; base = OW0_OFF; K = 64;  N = 256; lstride = 16640; skip = 1; f -= OW0_OFF; }
  else if (f < OW2_OFF) { W = odeW1; base = OW1_OFF; K = 256; N = 256; lstride = 65536; skip = 0; f -= OW1_OFF; }
  else if (f < NW0_OFF) { W = odeW2; base = OW2_OFF; K = 256; N = 64;  lstride = 16384; skip = 0; f -= OW2_OFF; }
  else if (f < NW1_OFF) { W = nvpW0; base = NW0_OFF; K = 32;  N = 256; lstride = 8192;  skip = 0; f -= NW0_OFF; }
  else if (f < NW2_OFF) { W = nvpW1; base = NW1_OFF; K = 256; N = 256; lstride = 65536; skip = 0; f -= NW1_OFF; }
  else                  { W = nvpW2; base = NW2_OFF; K = 256; N = 64;  lstride = 16384; skip = 0; f -= NW2_OFF; }
  int per   = K * N;
  int layer = f / per;
  int e     = f - layer * per;
  int j  = e & 7;
  int l  = (e >> 3) & 63;
  int t  = e >> 9;                 // nt*KS + ks
  int KS = K >> 5; if (KS < 1) KS = 1;
  int ks = t % KS;
  int nt = t / KS;
  int n = nt * 16 + (l & 15);
  int k = ks * 32 + ((l >> 4) << 3) + j;
  ws[base + layer * per + e] = f2bfu(W[layer * lstride + (k + skip) * N + n]);
}

// store 4 consecutive n of batch-row m as bf16 into h1 [m][256], swz (m&15)<<4
__device__ __forceinline__ void st_h(char* dst, int m, int n0, float a, float b, float c, float d) {
  int off = (m * 512 + n0 * 2) ^ ((m & 15) << 4);
  *reinterpret_cast<unsigned long long*>(dst + off) = pack4bf(a, b, c, d);
}

__device__ __forceinline__ void bn_apply(float y[8], const float* __restrict__ mptr,
                                         const float* __restrict__ vptr, const float* __restrict__ gptr,
                                         const float* __restrict__ bptr, int d0) {
  floatx4 mm = *reinterpret_cast<const floatx4*>(mptr + d0);
  floatx4 vv = *reinterpret_cast<const floatx4*>(vptr + d0);
  floatx4 gg = *reinterpret_cast<const floatx4*>(gptr + d0);
  floatx4 be = *reinterpret_cast<const floatx4*>(bptr + d0);
  float sc[4];
  #pragma unroll
  for (int p = 0; p < 4; ++p) sc[p] = sqrtf(vv[p] + EPSV) / gg[p];
  #pragma unroll
  for (int mt = 0; mt < 2; ++mt)
    #pragma unroll
    for (int p = 0; p < 4; ++p)
      y[mt * 4 + p] = (y[mt * 4 + p] - be[p]) * sc[p] + mm[p];
}

// ---------------- fused flow kernel: 1024 threads, 16 waves ----------------
__global__ void
__launch_bounds__(1024)
flow_kernel(const float* __restrict__ xin,
            const float* __restrict__ nvp_b0, const float* __restrict__ nvp_b1,
            const float* __restrict__ nvp_b2,
            const float* __restrict__ odeW0_full,
            const float* __restrict__ ode_b0, const float* __restrict__ ode_b1,
            const float* __restrict__ ode_b2,
            const float* __restrict__ bn1m, const float* __restrict__ bn1v,
            const float* __restrict__ bn1g, const float* __restrict__ bn1b,
            const float* __restrict__ bn2m, const float* __restrict__ bn2v,
            const float* __restrict__ bn2g, const float* __restrict__ bn2b,
            const unsigned short* __restrict__ ws,
            float* __restrict__ out) {
  __shared__ __align__(16) char smem[LDS_SIZE];
  char*  h1   = smem + H1_OFF;
  char*  ysb  = smem + YS_OFF;
  char*  yinb = smem + YIN_OFF;
  char*  shfb = smem + SHF_OFF;
  short8* w2f = reinterpret_cast<short8*>(smem + W2B_OFF);
  float* pars = reinterpret_cast<float*>(smem + PARS_OFF);

  const floatx4 zero4 = {0.f, 0.f, 0.f, 0.f};

  const int tid  = threadIdx.x;
  const int lane = tid & 63;
  const int w    = tid >> 6;       // wave 0..15
  const int l15  = lane & 15;
  const int g    = lane >> 4;
  const int wn   = w & 3;          // y/G3 n-slice (16 of 64 dims)
  const int wm   = w >> 2;         // y/G3 m-quarter (32 of 128 rows)
  const int nb0  = w * 16 + g * 4; // G1/G2 output n-base
  const int row0 = blockIdx.x * 128 + wm * 32;
  const int d0   = wn * 16 + g * 4;
  const float dtv = 1.0f / NSTEP;

  float y[8];  // y[mt*4+p] at row (row0 + mt*16 + l15), dim (d0 + p), mt in {0,1}
  #pragma unroll
  for (int mt = 0; mt < 2; ++mt) {
    floatx4 v = *reinterpret_cast<const floatx4*>(xin + (row0 + mt * 16 + l15) * 64 + d0);
    y[mt * 4 + 0] = v[0]; y[mt * 4 + 1] = v[1]; y[mt * 4 + 2] = v[2]; y[mt * 4 + 3] = v[3];
  }

  short8 aw0[2];   // G1 A-frags (wave's 16-wide n-slice; ks=0..1; NVP uses [0] only)
  short8 aw1[8];   // G2 A-frags

  for (int l = 0; l < LNUM; ++l) {
    // ---- NVP weight slices into registers ----
    {
      const short8* p0 = reinterpret_cast<const short8*>(ws + NW0_OFF + l * 8192);
      const short8* p1 = reinterpret_cast<const short8*>(ws + NW1_OFF + l * 65536);
      aw0[0] = p0[w * 64 + lane];                       // KS=1, nt=w
      #pragma unroll
      for (int ks = 0; ks < 8; ++ks) aw1[ks] = p1[(w * 8 + ks) * 64 + lane];
    }

    // ================= perm + RealNVP =================
    __syncthreads();                       // prev-layer LDS readers done
    #pragma unroll
    for (int mt = 0; mt < 2; ++mt) {       // stash y fp32 into ys (swz m&15)
      int m = wm * 32 + mt * 16 + l15;
      floatx4 v = {y[mt * 4 + 0], y[mt * 4 + 1], y[mt * 4 + 2], y[mt * 4 + 3]};
      int off = (m * 256 + d0 * 4) ^ ((m & 15) << 4);
      *reinterpret_cast<floatx4*>(ysb + off) = v;
    }
    if (wn >= 2) {                         // x0 (= y dims 32..63) bf16 into yin (swz m&7)
      #pragma unroll
      for (int mt = 0; mt < 2; ++mt) {
        int m = wm * 32 + mt * 16 + l15;
        int off = (m * 128 + (d0 - 32) * 2) ^ ((m & 7) << 4);
        *reinterpret_cast<unsigned long long*>(yinb + off) =
            pack4bf(y[mt * 4 + 0], y[mt * 4 + 1], y[mt * 4 + 2], y[mt * 4 + 3]);
      }
    }
    for (int i = tid; i < 576; i += 1024) { // NVP biases
      float v;
      if (i < 256)      v = nvp_b0[l * 256 + i];
      else if (i < 512) v = nvp_b1[l * 256 + i - 256];
      else              v = nvp_b2[l * 64 + i - 512];
      pars[i] = v;
    }
    {                                      // NVP W2 fragments -> LDS
      const short8* src = reinterpret_cast<const short8*>(ws + NW2_OFF + l * 16384);
      for (int i = tid; i < 2048; i += 1024) w2f[i] = src[i];
    }
    __syncthreads();

    // ---- NVP G1: h1 = relu(x0 @ W0n + b0n), K=32, 8 m-tiles in 2 batches ----
    {
      floatx4 b0v = *reinterpret_cast<const floatx4*>(pars + nb0);
      #pragma unroll
      for (int b = 0; b < 2; ++b) {
        floatx4 acc[4];
        short8 B[4];
        #pragma unroll
        for (int mt = 0; mt < 4; ++mt) {
          int m = b * 64 + mt * 16 + l15;
          int off = (m * 128 + g * 16) ^ ((m & 7) << 4);
          B[mt] = *reinterpret_cast<const short8*>(yinb + off);
        }
        #pragma unroll
        for (int mt = 0; mt < 4; ++mt) acc[mt] = MF(aw0[0], B[mt], zero4);
        #pragma unroll
        for (int mt = 0; mt < 4; ++mt) {
          int m = b * 64 + mt * 16 + l15;
          st_h(h1, m, nb0,
               fmaxf(acc[mt][0] + b0v[0], 0.f), fmaxf(acc[mt][1] + b0v[1], 0.f),
               fmaxf(acc[mt][2] + b0v[2], 0.f), fmaxf(acc[mt][3] + b0v[3], 0.f));
        }
      }
    }
    __syncthreads();

    // ---- NVP G2: relu(h1 @ W1n + b1n), in-place h1, 2 m-halves ----
    {
      floatx4 b1v = *reinterpret_cast<const floatx4*>(pars + 256 + nb0);
      #pragma unroll
      for (int mh = 0; mh < 2; ++mh) {
        floatx4 acc[4];
        #pragma unroll
        for (int mt = 0; mt < 4; ++mt) acc[mt] = zero4;
        #pragma unroll
        for (int ks = 0; ks < 8; ++ks) {
          short8 B[4];
          #pragma unroll
          for (int mt = 0; mt < 4; ++mt) {
            int m = mh * 64 + mt * 16 + l15;
            int off = (m * 512 + (ks * 32 + g * 8) * 2) ^ ((m & 15) << 4);
            B[mt] = *reinterpret_cast<const short8*>(h1 + off);
          }
          #pragma unroll
          for (int mt = 0; mt < 4; ++mt) acc[mt] = MF(aw1[ks], B[mt], acc[mt]);
        }
        __syncthreads();                   // all reads of this half's rows done
        #pragma unroll
        for (int mt = 0; mt < 4; ++mt) {
          int m = mh * 64 + mt * 16 + l15;
          st_h(h1, m, nb0,
               fmaxf(acc[mt][0] + b1v[0], 0.f), fmaxf(acc[mt][1] + b1v[1], 0.f),
               fmaxf(acc[mt][2] + b1v[2], 0.f), fmaxf(acc[mt][3] + b1v[3], 0.f));
        }
      }
    }
    __syncthreads();

    // ---- NVP G3: [shift|logscale] = h2 @ W2n + b2n  (A from LDS w2f) ----
    floatx4 a3[2];
    a3[0] = zero4;
    a3[1] = zero4;
    #pragma unroll
    for (int ks = 0; ks < 8; ++ks) {
      short8 A = w2f[(wn * 8 + ks) * 64 + lane];
      #pragma unroll
      for (int mt = 0; mt < 2; ++mt) {
        int m = wm * 32 + mt * 16 + l15;
        int off = (m * 512 + (ks * 32 + g * 8) * 2) ^ ((m & 15) << 4);
        short8 B = *reinterpret_cast<const short8*>(h1 + off);
        a3[mt] = MF(A, B, a3[mt]);
      }
    }
    {
      floatx4 b2v = *reinterpret_cast<const floatx4*>(pars + 512 + d0);
      #pragma unroll
      for (int mt = 0; mt < 2; ++mt)
        #pragma unroll
        for (int p = 0; p < 4; ++p) a3[mt][p] += b2v[p];
    }

    // ---- ODE weight slices into registers (overwrites NVP slices, dead now) ----
    {
      const short8* p0 = reinterpret_cast<const short8*>(ws + OW0_OFF + l * 16384);
      const short8* p1 = reinterpret_cast<const short8*>(ws + OW1_OFF + l * 65536);
      #pragma unroll
      for (int ks = 0; ks < 2; ++ks) aw0[ks] = p0[(w * 2 + ks) * 64 + lane];
      #pragma unroll
      for (int ks = 0; ks < 8; ++ks) aw1[ks] = p1[(w * 8 + ks) * 64 + lane];
    }

    if (wn < 2) {                          // stash shift (dims 0..31) bf16
      #pragma unroll
      for (int mt = 0; mt < 2; ++mt) {
        int m = wm * 32 + mt * 16 + l15;
        int off = (m * 64 + d0 * 2) ^ ((m & 3) << 4);
        *reinterpret_cast<unsigned long long*>(shfb + off) =
            pack4bf(a3[mt][0], a3[mt][1], a3[mt][2], a3[mt][3]);
      }
    }
    __syncthreads();                       // G3 w2f/h1 reads + shift writes done
    if (wn < 2) {                          // new y[d<32] = old y[d+32]
      #pragma unroll
      for (int mt = 0; mt < 2; ++mt) {
        int m = wm * 32 + mt * 16 + l15;
        int off = (m * 256 + (d0 + 32) * 4) ^ ((m & 15) << 4);
        floatx4 v = *reinterpret_cast<const floatx4*>(ysb + off);
        y[mt * 4 + 0] = v[0]; y[mt * 4 + 1] = v[1]; y[mt * 4 + 2] = v[2]; y[mt * 4 + 3] = v[3];
      }
    } else {                               // new y[32+j] = x1[j]*exp(ls[j]) + shift[j]
      #pragma unroll
      for (int mt = 0; mt < 2; ++mt) {
        int m = wm * 32 + mt * 16 + l15;
        int offx = (m * 256 + (d0 - 32) * 4) ^ ((m & 15) << 4);
        floatx4 x1 = *reinterpret_cast<const floatx4*>(ysb + offx);
        int offs = (m * 64 + (d0 - 32) * 2) ^ ((m & 3) << 4);
        unsigned long long u = *reinterpret_cast<const unsigned long long*>(shfb + offs);
        y[mt * 4 + 0] = x1[0] * __expf(a3[mt][0]) + bfu2f((unsigned short)(u));
        y[mt * 4 + 1] = x1[1] * __expf(a3[mt][1]) + bfu2f((unsigned short)(u >> 16));
        y[mt * 4 + 2] = x1[2] * __expf(a3[mt][2]) + bfu2f((unsigned short)(u >> 32));
        y[mt * 4 + 3] = x1[3] * __expf(a3[mt][3]) + bfu2f((unsigned short)(u >> 48));
      }
    }
    bn_apply(y, bn1m + l * 64, bn1v + l * 64, bn1g + l * 64, bn1b + l * 64, d0);

    for (int i = tid; i < 832; i += 1024) { // ODE biases + t-row
      float v;
      if (i < 256)      v = ode_b0[l * 256 + i];
      else if (i < 512) v = ode_b1[l * 256 + i - 256];
      else if (i < 576) v = ode_b2[l * 64 + i - 512];
      else              v = odeW0_full[l * 16640 + i - 576];
      pars[i] = v;
    }
    {                                      // ODE W2 fragments -> LDS
      const short8* src = reinterpret_cast<const short8*>(ws + OW2_OFF + l * 16384);
      for (int i = tid; i < 2048; i += 1024) w2f[i] = src[i];
    }

    // ================= FFJORD: 8 RK4 steps =================
    float ka[8], kc[8];
    for (int s = 0; s < NSTEP; ++s) {
      float t0 = (float)s * dtv;
      for (int stg = 0; stg < 4; ++stg) {
        float cadd = (stg == 0) ? 0.0f : ((stg == 3) ? dtv : 0.5f * dtv);
        float tcur = t0 + cadd;
        #pragma unroll
        for (int mt = 0; mt < 2; ++mt) {   // yin bf16 [128][64], swz m&7
          int m = wm * 32 + mt * 16 + l15;
          float v0, v1, v2, v3;
          if (stg == 0) {
            v0 = y[mt * 4 + 0]; v1 = y[mt * 4 + 1]; v2 = y[mt * 4 + 2]; v3 = y[mt * 4 + 3];
          } else {
            v0 = fmaf(cadd, kc[mt * 4 + 0], y[mt * 4 + 0]);
            v1 = fmaf(cadd, kc[mt * 4 + 1], y[mt * 4 + 1]);
            v2 = fmaf(cadd, kc[mt * 4 + 2], y[mt * 4 + 2]);
            v3 = fmaf(cadd, kc[mt * 4 + 3], y[mt * 4 + 3]);
          }
          int off = (m * 128 + d0 * 2) ^ ((m & 7) << 4);
          *reinterpret_cast<unsigned long long*>(yinb + off) = pack4bf(v0, v1, v2, v3);
        }
        __syncthreads();                   // yin ready; prev-eval G3 h1-reads done

        // G1: h1 = tanh(yin @ W0o + b0o + tcur*w0row0), K=64, 8 m-tiles in 2 batches
        {
          floatx4 bb = *reinterpret_cast<const floatx4*>(pars + nb0);
          floatx4 w0 = *reinterpret_cast<const floatx4*>(pars + 576 + nb0);
          float c0 = bb[0] + tcur * w0[0], c1 = bb[1] + tcur * w0[1];
          float c2 = bb[2] + tcur * w0[2], c3 = bb[3] + tcur * w0[3];
          #pragma unroll
          for (int b = 0; b < 2; ++b) {
            floatx4 acc[4];
            #pragma unroll
            for (int mt = 0; mt < 4; ++mt) acc[mt] = zero4;
            #pragma unroll
            for (int ks = 0; ks < 2; ++ks) {
              short8 B[4];
              #pragma unroll
              for (int mt = 0; mt < 4; ++mt) {
                int m = b * 64 + mt * 16 + l15;
                int off = (m * 128 + (ks * 32 + g * 8) * 2) ^ ((m & 7) << 4);
                B[mt] = *reinterpret_cast<const short8*>(yinb + off);
              }
              #pragma unroll
              for (int mt = 0; mt < 4; ++mt) acc[mt] = MF(aw0[ks], B[mt], acc[mt]);
            }
            #pragma unroll
            for (int mt = 0; mt < 4; ++mt) {
              int m = b * 64 + mt * 16 + l15;
              st_h(h1, m, nb0,
                   tanh_fast(acc[mt][0] + c0), tanh_fast(acc[mt][1] + c1),
                   tanh_fast(acc[mt][2] + c2), tanh_fast(acc[mt][3] + c3));
            }
          }
        }
        __syncthreads();

        // G2: h2 = tanh(h1 @ W1o + b1o), in-place h1, 2 m-halves
        {
          floatx4 b1v = *reinterpret_cast<const floatx4*>(pars + 256 + nb0);
          #pragma unroll
          for (int mh = 0; mh < 2; ++mh) {
            floatx4 acc[4];
            #pragma unroll
            for (int mt = 0; mt < 4; ++mt) acc[mt] = zero4;
            #pragma unroll
            for (int ks = 0; ks < 8; ++ks) {
              short8 B[4];
              #pragma unroll
              for (int mt = 0; mt < 4; ++mt) {
                int m = mh * 64 + mt * 16 + l15;
                int off = (m * 512 + (ks * 32 + g * 8) * 2) ^ ((m & 15) << 4);
                B[mt] = *reinterpret_cast<const short8*>(h1 + off);
              }
              #pragma unroll
              for (int mt = 0; mt < 4; ++mt) acc[mt] = MF(aw1[ks], B[mt], acc[mt]);
            }
            __syncthreads();
            #pragma unroll
            for (int mt = 0; mt < 4; ++mt) {
              int m = mh * 64 + mt * 16 + l15;
              st_h(h1, m, nb0,
                   tanh_fast(acc[mt][0] + b1v[0]), tanh_fast(acc[mt][1] + b1v[1]),
                   tanh_fast(acc[mt][2] + b1v[2]), tanh_fast(acc[mt][3] + b1v[3]));
            }
          }
        }
        __syncthreads();

        // G3: k = h2 @ W2o + b2o  (A from LDS w2f)
        {
          floatx4 a2[2];
          a2[0] = zero4;
          a2[1] = zero4;
          #pragma unroll
          for (int ks = 0; ks < 8; ++ks) {
            short8 A = w2f[(wn * 8 + ks) * 64 + lane];
            #pragma unroll
            for (int mt = 0; mt < 2; ++mt) {
              int m = wm * 32 + mt * 16 + l15;
              int off = (m * 512 + (ks * 32 + g * 8) * 2) ^ ((m & 15) << 4);
              short8 B = *reinterpret_cast<const short8*>(h1 + off);
              a2[mt] = MF(A, B, a2[mt]);
            }
          }
          floatx4 b2v = *reinterpret_cast<const floatx4*>(pars + 512 + d0);
          #pragma unroll
          for (int mt = 0; mt < 2; ++mt)
            #pragma unroll
            for (int p = 0; p < 4; ++p)
              kc[mt * 4 + p] = a2[mt][p] + b2v[p];
        }
        if (stg == 0) {
          #pragma unroll
          for (int i = 0; i < 8; ++i) ka[i] = kc[i];
        } else if (stg == 3) {
          #pragma unroll
          for (int i = 0; i < 8; ++i) ka[i] += kc[i];
        } else {
          #pragma unroll
          for (int i = 0; i < 8; ++i) ka[i] += 2.0f * kc[i];
        }
      }
      #pragma unroll
      for (int i = 0; i < 8; ++i) y[i] += (dtv / 6.0f) * ka[i];
    }

    bn_apply(y, bn2m + l * 64, bn2v + l * 64, bn2g + l * 64, bn2b + l * 64, d0);
  }

  #pragma unroll
  for (int mt = 0; mt < 2; ++mt) {
    floatx4 v = {y[mt * 4 + 0], y[mt * 4 + 1], y[mt * 4 + 2], y[mt * 4 + 3]};
    *reinterpret_cast<floatx4*>(out + (row0 + mt * 16 + l15) * 64 + d0) = v;
  }
}

extern "C" void kernel_launch(void* const* d_in, const int* in_sizes, int n_in,
                              void* d_out, int out_size, void* d_ws, size_t ws_size,
                              hipStream_t stream) {
  const float* x      = (const float*)d_in[0];
  const float* nvpW0  = (const float*)d_in[2];
  const float* nvp_b0 = (const float*)d_in[3];
  const float* nvpW1  = (const float*)d_in[4];
  const float* nvp_b1 = (const float*)d_in[5];
  const float* nvpW2  = (const float*)d_in[6];
  const float* nvp_b2 = (const float*)d_in[7];
  const float* odeW0  = (const float*)d_in[8];
  const float* ode_b0 = (const float*)d_in[9];
  const float* odeW1  = (const float*)d_in[10];
  const float* ode_b1 = (const float*)d_in[11];
  const float* odeW2  = (const float*)d_in[12];
  const float* ode_b2 = (const float*)d_in[13];
  const float* bn1m   = (const float*)d_in[14];
  const float* bn1v   = (const float*)d_in[15];
  const float* bn1g   = (const float*)d_in[16];
  const float* bn1b   = (const float*)d_in[17];
  const float* bn2m   = (const float*)d_in[18];
  const float* bn2v   = (const float*)d_in[19];
  const float* bn2g   = (const float*)d_in[20];
  const float* bn2b   = (const float*)d_in[21];
  unsigned short* ws  = (unsigned short*)d_ws;
  float* out          = (float*)d_out;

  int pblocks = (WS_ELEMS + 255) / 256;
  prep_kernel<<<pblocks, 256, 0, stream>>>(odeW0, odeW1, odeW2, nvpW0, nvpW1, nvpW2, ws);
  flow_kernel<<<256, 1024, 0, stream>>>(x, nvp_b0, nvp_b1, nvp_b2, odeW0,
                                        ode_b0, ode_b1, ode_b2,
                                        bn1m, bn1v, bn1g, bn1b,
                                        bn2m, bn2v, bn2g, bn2b,
                                        ws, out);
}

// Round 8
// 2246.071 us; speedup vs baseline: 1.6212x; 1.6212x over previous
//
#include <hip/hip_runtime.h>

// StackedFlow v7: v5 structure (512 thr, static LDS) + amdgpu_num_vgpr(256) + (m&15) swizzle.
// r7 findings: allocator budget = 65536/blockDim VGPRs (512->128, 1024->64) regardless of
// launch_bounds / waves_per_eu / static LDS; v5's WRITE 91MB = ~83MB scratch spill stores
// (reloads L2-cached, FETCH was mostly legitimate weight loads). num_vgpr is the remaining
// hard override for the 212-reg demand. (m&15)<<4 swizzle (from v6b) cut bank conflicts
// 1.43e8 -> 3.9e7; applied to h1 and ys (RS>=256 only; yin stays (m&7), 16B-align constraint).

#define LNUM   4
#define NSTEP  8
#define EPSV   1e-3f

typedef __attribute__((ext_vector_type(8))) short  short8;
typedef __attribute__((ext_vector_type(4))) float  floatx4;

#define MF(a, b, c) __builtin_amdgcn_mfma_f32_16x16x32_bf16((a), (b), (c), 0, 0, 0)

// d_ws layout (bf16 element offsets), per-GEMM fragment arrays [layer][nt*KS+ks][lane][8]
#define OW0_OFF 0        // ode W0 rows 1..64  (64 x 256)
#define OW1_OFF 65536    // ode W1            (256 x 256)
#define OW2_OFF 327680   // ode W2            (256 x 64)
#define NW0_OFF 393216   // nvp W0            (32 x 256)
#define NW1_OFF 425984   // nvp W1            (256 x 256)
#define NW2_OFF 688128   // nvp W2            (256 x 64)
#define WS_ELEMS 753664

// LDS byte offsets
#define H1_OFF   0        // 64K bf16 [128][256] RS=512 swz((m&15)<<4)
#define YS_OFF   65536    // 32K fp32 [128][64]  RS=256 swz((m&15)<<4)
#define YIN_OFF  98304    // 16K bf16 [128][64]  RS=128 swz((m&7)<<4)   (x0 in NVP phase)
#define SHF_OFF  114688   // 8K  bf16 [128][32]  RS=64  swz((m&3)<<4)
#define W2B_OFF  122880   // 32K short8[2048] W2 fragments (NVP then ODE)
#define PARS_OFF 155648   // 3328B: b0 | b1(+256) | b2(+512) | w0row0(+576)
#define LDS_SIZE 158976

__device__ __forceinline__ unsigned short f2bfu(float f) {
  unsigned int u = __float_as_uint(f);
  return (unsigned short)((u + 0x7FFFu + ((u >> 16) & 1u)) >> 16);  // RNE
}

__device__ __forceinline__ unsigned long long pack4bf(float a, float b, float c, float d) {
  return (unsigned long long)f2bfu(a)
       | ((unsigned long long)f2bfu(b) << 16)
       | ((unsigned long long)f2bfu(c) << 32)
       | ((unsigned long long)f2bfu(d) << 48);
}

__device__ __forceinline__ float bfu2f(unsigned short u) {
  return __uint_as_float((unsigned int)u << 16);
}

__device__ __forceinline__ float tanh_fast(float x) {
  float e = __expf(2.0f * x);
  return 1.0f - 2.0f * __builtin_amdgcn_rcpf(e + 1.0f);
}

// ---------------- weight prep: fp32 [K][N] -> bf16 A-fragment order ----------------
__global__ void prep_kernel(const float* __restrict__ odeW0, const float* __restrict__ odeW1,
                            const float* __restrict__ odeW2, const float* __restrict__ nvpW0,
                            const float* __restrict__ nvpW1, const float* __restrict__ nvpW2,
                            unsigned short* __restrict__ ws) {
  int idx = blockIdx.x * blockDim.x + threadIdx.x;
  if (idx >= WS_ELEMS) return;
  const float* W; int base, K, N, lstride, skip;
  int f = idx;
  if (f < OW1_OFF)      { W = odeW0; base = OW0_OFF; K = 64;  N = 256; lstride = 16640; skip = 1; f -= OW0_OFF; }
  else if (f < OW2_OFF) { W = odeW1; base = OW1_OFF; K = 256; N = 256; lstride = 65536; skip = 0; f -= OW1_OFF; }
  else if (f < NW0_OFF) { W = odeW2; base = OW2_OFF; K = 256; N = 64;  lstride = 16384; skip = 0; f -= OW2_OFF; }
  else if (f < NW1_OFF) { W = nvpW0; base = NW0_OFF; K = 32;  N = 256; lstride = 8192;  skip = 0; f -= NW0_OFF; }
  else if (f < NW2_OFF) { W = nvpW1; base = NW1_OFF; K = 256; N = 256; lstride = 65536; skip = 0; f -= NW1_OFF; }
  else                  { W = nvpW2; base = NW2_OFF; K = 256; N = 64;  lstride = 16384; skip = 0; f -= NW2_OFF; }
  int per   = K * N;
  int layer = f / per;
  int e     = f - layer * per;
  int j  = e & 7;
  int l  = (e >> 3) & 63;
  int t  = e >> 9;                 // nt*KS + ks
  int KS = K >> 5; if (KS < 1) KS = 1;
  int ks = t % KS;
  int nt = t / KS;
  int n = nt * 16 + (l & 15);
  int k = ks * 32 + ((l >> 4) << 3) + j;
  ws[base + layer * per + e] = f2bfu(W[layer * lstride + (k + skip) * N + n]);
}

// store 4 consecutive n of batch-row m as bf16 into h1 [m][256], swz (m&15)<<4
__device__ __forceinline__ void st_h(char* dst, int m, int n0, float a, float b, float c, float d) {
  int off = (m * 512 + n0 * 2) ^ ((m & 15) << 4);
  *reinterpret_cast<unsigned long long*>(dst + off) = pack4bf(a, b, c, d);
}

__device__ __forceinline__ void bn_apply(float y[16], const float* __restrict__ mptr,
                                         const float* __restrict__ vptr, const float* __restrict__ gptr,
                                         const float* __restrict__ bptr, int d0) {
  floatx4 mm = *reinterpret_cast<const floatx4*>(mptr + d0);
  floatx4 vv = *reinterpret_cast<const floatx4*>(vptr + d0);
  floatx4 gg = *reinterpret_cast<const floatx4*>(gptr + d0);
  floatx4 be = *reinterpret_cast<const floatx4*>(bptr + d0);
  float sc[4];
  #pragma unroll
  for (int p = 0; p < 4; ++p) sc[p] = sqrtf(vv[p] + EPSV) / gg[p];
  #pragma unroll
  for (int mt = 0; mt < 4; ++mt)
    #pragma unroll
    for (int p = 0; p < 4; ++p)
      y[mt * 4 + p] = (y[mt * 4 + p] - be[p]) * sc[p] + mm[p];
}

// ---------------- fused flow kernel ----------------
__global__ void
__launch_bounds__(512)
__attribute__((amdgpu_num_vgpr(256)))
flow_kernel(const float* __restrict__ xin,
            const float* __restrict__ nvp_b0, const float* __restrict__ nvp_b1,
            const float* __restrict__ nvp_b2,
            const float* __restrict__ odeW0_full,
            const float* __restrict__ ode_b0, const float* __restrict__ ode_b1,
            const float* __restrict__ ode_b2,
            const float* __restrict__ bn1m, const float* __restrict__ bn1v,
            const float* __restrict__ bn1g, const float* __restrict__ bn1b,
            const float* __restrict__ bn2m, const float* __restrict__ bn2v,
            const float* __restrict__ bn2g, const float* __restrict__ bn2b,
            const unsigned short* __restrict__ ws,
            float* __restrict__ out) {
  __shared__ __align__(16) char smem[LDS_SIZE];
  char*  h1   = smem + H1_OFF;
  char*  ysb  = smem + YS_OFF;
  char*  yinb = smem + YIN_OFF;
  char*  shfb = smem + SHF_OFF;
  short8* w2f = reinterpret_cast<short8*>(smem + W2B_OFF);
  float* pars = reinterpret_cast<float*>(smem + PARS_OFF);

  const floatx4 zero4 = {0.f, 0.f, 0.f, 0.f};

  const int tid  = threadIdx.x;
  const int lane = tid & 63;
  const int w    = tid >> 6;
  const int l15  = lane & 15;
  const int g    = lane >> 4;
  const int wn   = w & 3;
  const int wm   = w >> 2;
  const int m0   = blockIdx.x * 128 + wm * 64;
  const int d0   = wn * 16 + g * 4;
  const float dtv = 1.0f / NSTEP;

  float y[16];  // y[mt*4+p] at row (m0 + mt*16 + l15), dim (d0 + p)
  #pragma unroll
  for (int mt = 0; mt < 4; ++mt) {
    floatx4 v = *reinterpret_cast<const floatx4*>(xin + (m0 + mt * 16 + l15) * 64 + d0);
    y[mt * 4 + 0] = v[0]; y[mt * 4 + 1] = v[1]; y[mt * 4 + 2] = v[2]; y[mt * 4 + 3] = v[3];
  }

  short8 aw0[2][2];   // G1 A-frags (wave's n-slice [32w, 32w+32))
  short8 aw1[2][8];   // G2 A-frags

  for (int l = 0; l < LNUM; ++l) {
    // ---- NVP weight slices into registers ----
    {
      const short8* p0 = reinterpret_cast<const short8*>(ws + NW0_OFF + l * 8192);
      const short8* p1 = reinterpret_cast<const short8*>(ws + NW1_OFF + l * 65536);
      #pragma unroll
      for (int nt = 0; nt < 2; ++nt) aw0[nt][0] = p0[(w * 2 + nt) * 64 + lane];
      #pragma unroll
      for (int nt = 0; nt < 2; ++nt)
        #pragma unroll
        for (int ks = 0; ks < 8; ++ks) aw1[nt][ks] = p1[((w * 2 + nt) * 8 + ks) * 64 + lane];
    }

    // ================= perm + RealNVP =================
    __syncthreads();                       // prev-layer LDS readers done
    #pragma unroll
    for (int mt = 0; mt < 4; ++mt) {       // stash y fp32 into ys (swz m&15)
      int m = wm * 64 + mt * 16 + l15;
      floatx4 v = {y[mt * 4 + 0], y[mt * 4 + 1], y[mt * 4 + 2], y[mt * 4 + 3]};
      int off = (m * 256 + d0 * 4) ^ ((m & 15) << 4);
      *reinterpret_cast<floatx4*>(ysb + off) = v;
    }
    if (wn >= 2) {                         // x0 (= y dims 32..63) bf16 into yin (swz m&7)
      #pragma unroll
      for (int mt = 0; mt < 4; ++mt) {
        int m = wm * 64 + mt * 16 + l15;
        int off = (m * 128 + (d0 - 32) * 2) ^ ((m & 7) << 4);
        *reinterpret_cast<unsigned long long*>(yinb + off) =
            pack4bf(y[mt * 4 + 0], y[mt * 4 + 1], y[mt * 4 + 2], y[mt * 4 + 3]);
      }
    }
    for (int i = tid; i < 576; i += 512) { // NVP biases
      float v;
      if (i < 256)      v = nvp_b0[l * 256 + i];
      else if (i < 512) v = nvp_b1[l * 256 + i - 256];
      else              v = nvp_b2[l * 64 + i - 512];
      pars[i] = v;
    }
    {                                      // NVP W2 fragments -> LDS
      const short8* src = reinterpret_cast<const short8*>(ws + NW2_OFF + l * 16384);
      for (int i = tid; i < 2048; i += 512) w2f[i] = src[i];
    }
    __syncthreads();

    // ---- NVP G1: h1 = relu(x0 @ W0n + b0n) ----
    #pragma unroll
    for (int mh = 0; mh < 2; ++mh) {
      floatx4 acc[2][4];
      #pragma unroll
      for (int nt = 0; nt < 2; ++nt)
        #pragma unroll
        for (int mt = 0; mt < 4; ++mt) acc[nt][mt] = zero4;
      short8 B[4];
      #pragma unroll
      for (int mt = 0; mt < 4; ++mt) {
        int m = mh * 64 + mt * 16 + l15;
        int off = (m * 128 + (g * 8) * 2) ^ ((m & 7) << 4);
        B[mt] = *reinterpret_cast<const short8*>(yinb + off);
      }
      #pragma unroll
      for (int nt = 0; nt < 2; ++nt)
        #pragma unroll
        for (int mt = 0; mt < 4; ++mt) acc[nt][mt] = MF(aw0[nt][0], B[mt], acc[nt][mt]);
      #pragma unroll
      for (int nt = 0; nt < 2; ++nt) {
        int nb = w * 32 + nt * 16 + g * 4;
        floatx4 bb = *reinterpret_cast<const floatx4*>(pars + nb);
        #pragma unroll
        for (int mt = 0; mt < 4; ++mt) {
          int m = mh * 64 + mt * 16 + l15;
          st_h(h1, m, nb,
               fmaxf(acc[nt][mt][0] + bb[0], 0.f), fmaxf(acc[nt][mt][1] + bb[1], 0.f),
               fmaxf(acc[nt][mt][2] + bb[2], 0.f), fmaxf(acc[nt][mt][3] + bb[3], 0.f));
        }
      }
    }
    __syncthreads();

    // ---- NVP G2: relu(h1 @ W1n + b1n), in-place h1 ----
    #pragma unroll
    for (int mh = 0; mh < 2; ++mh) {
      floatx4 acc[2][4];
      #pragma unroll
      for (int nt = 0; nt < 2; ++nt)
        #pragma unroll
        for (int mt = 0; mt < 4; ++mt) acc[nt][mt] = zero4;
      #pragma unroll
      for (int ks = 0; ks < 8; ++ks) {
        short8 B[4];
        #pragma unroll
        for (int mt = 0; mt < 4; ++mt) {
          int m = mh * 64 + mt * 16 + l15;
          int off = (m * 512 + (ks * 32 + g * 8) * 2) ^ ((m & 15) << 4);
          B[mt] = *reinterpret_cast<const short8*>(h1 + off);
        }
        #pragma unroll
        for (int nt = 0; nt < 2; ++nt)
          #pragma unroll
          for (int mt = 0; mt < 4; ++mt) acc[nt][mt] = MF(aw1[nt][ks], B[mt], acc[nt][mt]);
      }
      __syncthreads();
      #pragma unroll
      for (int nt = 0; nt < 2; ++nt) {
        int nb = w * 32 + nt * 16 + g * 4;
        floatx4 bb = *reinterpret_cast<const floatx4*>(pars + 256 + nb);
        #pragma unroll
        for (int mt = 0; mt < 4; ++mt) {
          int m = mh * 64 + mt * 16 + l15;
          st_h(h1, m, nb,
               fmaxf(acc[nt][mt][0] + bb[0], 0.f), fmaxf(acc[nt][mt][1] + bb[1], 0.f),
               fmaxf(acc[nt][mt][2] + bb[2], 0.f), fmaxf(acc[nt][mt][3] + bb[3], 0.f));
        }
      }
    }
    __syncthreads();

    // ---- NVP G3: [shift|logscale] = h2 @ W2n + b2n  (A from LDS w2f) ----
    floatx4 a3[4];
    #pragma unroll
    for (int mt = 0; mt < 4; ++mt) a3[mt] = zero4;
    #pragma unroll
    for (int ks = 0; ks < 8; ++ks) {
      short8 A = w2f[(wn * 8 + ks) * 64 + lane];
      #pragma unroll
      for (int mt = 0; mt < 4; ++mt) {
        int m = wm * 64 + mt * 16 + l15;
        int off = (m * 512 + (ks * 32 + g * 8) * 2) ^ ((m & 15) << 4);
        short8 B = *reinterpret_cast<const short8*>(h1 + off);
        a3[mt] = MF(A, B, a3[mt]);
      }
    }
    {
      floatx4 b2v = *reinterpret_cast<const floatx4*>(pars + 512 + d0);
      #pragma unroll
      for (int mt = 0; mt < 4; ++mt)
        #pragma unroll
        for (int p = 0; p < 4; ++p) a3[mt][p] += b2v[p];
    }

    // ---- ODE weight slices into registers ----
    {
      const short8* p0 = reinterpret_cast<const short8*>(ws + OW0_OFF + l * 16384);
      const short8* p1 = reinterpret_cast<const short8*>(ws + OW1_OFF + l * 65536);
      #pragma unroll
      for (int nt = 0; nt < 2; ++nt)
        #pragma unroll
        for (int ks = 0; ks < 2; ++ks) aw0[nt][ks] = p0[((w * 2 + nt) * 2 + ks) * 64 + lane];
      #pragma unroll
      for (int nt = 0; nt < 2; ++nt)
        #pragma unroll
        for (int ks = 0; ks < 8; ++ks) aw1[nt][ks] = p1[((w * 2 + nt) * 8 + ks) * 64 + lane];
    }

    if (wn < 2) {                          // stash shift (dims 0..31) bf16
      #pragma unroll
      for (int mt = 0; mt < 4; ++mt) {
        int m = wm * 64 + mt * 16 + l15;
        int off = (m * 64 + d0 * 2) ^ ((m & 3) << 4);
        *reinterpret_cast<unsigned long long*>(shfb + off) =
            pack4bf(a3[mt][0], a3[mt][1], a3[mt][2], a3[mt][3]);
      }
    }
    __syncthreads();                       // G3 w2f/h1 reads + shift writes done
    if (wn < 2) {                          // new y[d<32] = old y[d+32]
      #pragma unroll
      for (int mt = 0; mt < 4; ++mt) {
        int m = wm * 64 + mt * 16 + l15;
        int off = (m * 256 + (d0 + 32) * 4) ^ ((m & 15) << 4);
        floatx4 v = *reinterpret_cast<const floatx4*>(ysb + off);
        y[mt * 4 + 0] = v[0]; y[mt * 4 + 1] = v[1]; y[mt * 4 + 2] = v[2]; y[mt * 4 + 3] = v[3];
      }
    } else {                               // new y[32+j] = x1[j]*exp(ls[j]) + shift[j]
      #pragma unroll
      for (int mt = 0; mt < 4; ++mt) {
        int m = wm * 64 + mt * 16 + l15;
        int offx = (m * 256 + (d0 - 32) * 4) ^ ((m & 15) << 4);
        floatx4 x1 = *reinterpret_cast<const floatx4*>(ysb + offx);
        int offs = (m * 64 + (d0 - 32) * 2) ^ ((m & 3) << 4);
        unsigned long long u = *reinterpret_cast<const unsigned long long*>(shfb + offs);
        y[mt * 4 + 0] = x1[0] * __expf(a3[mt][0]) + bfu2f((unsigned short)(u));
        y[mt * 4 + 1] = x1[1] * __expf(a3[mt][1]) + bfu2f((unsigned short)(u >> 16));
        y[mt * 4 + 2] = x1[2] * __expf(a3[mt][2]) + bfu2f((unsigned short)(u >> 32));
        y[mt * 4 + 3] = x1[3] * __expf(a3[mt][3]) + bfu2f((unsigned short)(u >> 48));
      }
    }
    bn_apply(y, bn1m + l * 64, bn1v + l * 64, bn1g + l * 64, bn1b + l * 64, d0);

    for (int i = tid; i < 832; i += 512) { // ODE biases + t-row
      float v;
      if (i < 256)      v = ode_b0[l * 256 + i];
      else if (i < 512) v = ode_b1[l * 256 + i - 256];
      else if (i < 576) v = ode_b2[l * 64 + i - 512];
      else              v = odeW0_full[l * 16640 + i - 576];
      pars[i] = v;
    }
    {                                      // ODE W2 fragments -> LDS
      const short8* src = reinterpret_cast<const short8*>(ws + OW2_OFF + l * 16384);
      for (int i = tid; i < 2048; i += 512) w2f[i] = src[i];
    }

    // ================= FFJORD: 8 RK4 steps =================
    float ka[16], kc[16];
    for (int s = 0; s < NSTEP; ++s) {
      float t0 = (float)s * dtv;
      for (int stg = 0; stg < 4; ++stg) {
        float cadd = (stg == 0) ? 0.0f : ((stg == 3) ? dtv : 0.5f * dtv);
        float tcur = t0 + cadd;
        #pragma unroll
        for (int mt = 0; mt < 4; ++mt) {   // yin bf16 [128][64] swz m&7
          int m = wm * 64 + mt * 16 + l15;
          float v0, v1, v2, v3;
          if (stg == 0) {
            v0 = y[mt * 4 + 0]; v1 = y[mt * 4 + 1]; v2 = y[mt * 4 + 2]; v3 = y[mt * 4 + 3];
          } else {
            v0 = fmaf(cadd, kc[mt * 4 + 0], y[mt * 4 + 0]);
            v1 = fmaf(cadd, kc[mt * 4 + 1], y[mt * 4 + 1]);
            v2 = fmaf(cadd, kc[mt * 4 + 2], y[mt * 4 + 2]);
            v3 = fmaf(cadd, kc[mt * 4 + 3], y[mt * 4 + 3]);
          }
          int off = (m * 128 + d0 * 2) ^ ((m & 7) << 4);
          *reinterpret_cast<unsigned long long*>(yinb + off) = pack4bf(v0, v1, v2, v3);
        }
        __syncthreads();                   // yin ready; prev G3 h1-reads done

        // G1: h1 = tanh(yin @ W0o + b0o + tcur*w0row0)
        #pragma unroll
        for (int mh = 0; mh < 2; ++mh) {
          floatx4 acc[2][4];
          #pragma unroll
          for (int nt = 0; nt < 2; ++nt)
            #pragma unroll
            for (int mt = 0; mt < 4; ++mt) acc[nt][mt] = zero4;
          #pragma unroll
          for (int ks = 0; ks < 2; ++ks) {
            short8 B[4];
            #pragma unroll
            for (int mt = 0; mt < 4; ++mt) {
              int m = mh * 64 + mt * 16 + l15;
              int off = (m * 128 + (ks * 32 + g * 8) * 2) ^ ((m & 7) << 4);
              B[mt] = *reinterpret_cast<const short8*>(yinb + off);
            }
            #pragma unroll
            for (int nt = 0; nt < 2; ++nt)
              #pragma unroll
              for (int mt = 0; mt < 4; ++mt) acc[nt][mt] = MF(aw0[nt][ks], B[mt], acc[nt][mt]);
          }
          #pragma unroll
          for (int nt = 0; nt < 2; ++nt) {
            int nb = w * 32 + nt * 16 + g * 4;
            floatx4 bb = *reinterpret_cast<const floatx4*>(pars + nb);
            floatx4 w0 = *reinterpret_cast<const floatx4*>(pars + 576 + nb);
            float c0 = bb[0] + tcur * w0[0], c1 = bb[1] + tcur * w0[1];
            float c2 = bb[2] + tcur * w0[2], c3 = bb[3] + tcur * w0[3];
            #pragma unroll
            for (int mt = 0; mt < 4; ++mt) {
              int m = mh * 64 + mt * 16 + l15;
              st_h(h1, m, nb,
                   tanh_fast(acc[nt][mt][0] + c0), tanh_fast(acc[nt][mt][1] + c1),
                   tanh_fast(acc[nt][mt][2] + c2), tanh_fast(acc[nt][mt][3] + c3));
            }
          }
        }
        __syncthreads();

        // G2: h2 = tanh(h1 @ W1o + b1o), in-place h1
        #pragma unroll
        for (int mh = 0; mh < 2; ++mh) {
          floatx4 acc[2][4];
          #pragma unroll
          for (int nt = 0; nt < 2; ++nt)
            #pragma unroll
            for (int mt = 0; mt < 4; ++mt) acc[nt][mt] = zero4;
          #pragma unroll
          for (int ks = 0; ks < 8; ++ks) {
            short8 B[4];
            #pragma unroll
            for (int mt = 0; mt < 4; ++mt) {
              int m = mh * 64 + mt * 16 + l15;
              int off = (m * 512 + (ks * 32 + g * 8) * 2) ^ ((m & 15) << 4);
              B[mt] = *reinterpret_cast<const short8*>(h1 + off);
            }
            #pragma unroll
            for (int nt = 0; nt < 2; ++nt)
              #pragma unroll
              for (int mt = 0; mt < 4; ++mt) acc[nt][mt] = MF(aw1[nt][ks], B[mt], acc[nt][mt]);
          }
          __syncthreads();
          #pragma unroll
          for (int nt = 0; nt < 2; ++nt) {
            int nb = w * 32 + nt * 16 + g * 4;
            floatx4 bb = *reinterpret_cast<const floatx4*>(pars + 256 + nb);
            #pragma unroll
            for (int mt = 0; mt < 4; ++mt) {
              int m = mh * 64 + mt * 16 + l15;
              st_h(h1, m, nb,
                   tanh_fast(acc[nt][mt][0] + bb[0]), tanh_fast(acc[nt][mt][1] + bb[1]),
                   tanh_fast(acc[nt][mt][2] + bb[2]), tanh_fast(acc[nt][mt][3] + bb[3]));
            }
          }
        }
        __syncthreads();

        // G3: k = h2 @ W2o + b2o  (A from LDS w2f)
        floatx4 a2[4];
        #pragma unroll
        for (int mt = 0; mt < 4; ++mt) a2[mt] = zero4;
        #pragma unroll
        for (int ks = 0; ks < 8; ++ks) {
          short8 A = w2f[(wn * 8 + ks) * 64 + lane];
          #pragma unroll
          for (int mt = 0; mt < 4; ++mt) {
            int m = wm * 64 + mt * 16 + l15;
            int off = (m * 512 + (ks * 32 + g * 8) * 2) ^ ((m & 15) << 4);
            short8 B = *reinterpret_cast<const short8*>(h1 + off);
            a2[mt] = MF(A, B, a2[mt]);
          }
        }
        {
          floatx4 b2v = *reinterpret_cast<const floatx4*>(pars + 512 + d0);
          #pragma unroll
          for (int mt = 0; mt < 4; ++mt)
            #pragma unroll
            for (int p = 0; p < 4; ++p)
              kc[mt * 4 + p] = a2[mt][p] + b2v[p];
        }
        if (stg == 0) {
          #pragma unroll
          for (int i = 0; i < 16; ++i) ka[i] = kc[i];
        } else if (stg == 3) {
          #pragma unroll
          for (int i = 0; i < 16; ++i) ka[i] += kc[i];
        } else {
          #pragma unroll
          for (int i = 0; i < 16; ++i) ka[i] += 2.0f * kc[i];
        }
      }
      #pragma unroll
      for (int i = 0; i < 16; ++i) y[i] += (dtv / 6.0f) * ka[i];
    }

    bn_apply(y, bn2m + l * 64, bn2v + l * 64, bn2g + l * 64, bn2b + l * 64, d0);
  }

  #pragma unroll
  for (int mt = 0; mt < 4; ++mt) {
    floatx4 v = {y[mt * 4 + 0], y[mt * 4 + 1], y[mt * 4 + 2], y[mt * 4 + 3]};
    *reinterpret_cast<floatx4*>(out + (m0 + mt * 16 + l15) * 64 + d0) = v;
  }
}

extern "C" void kernel_launch(void* const* d_in, const int* in_sizes, int n_in,
                              void* d_out, int out_size, void* d_ws, size_t ws_size,
                              hipStream_t stream) {
  const float* x      = (const float*)d_in[0];
  const float* nvpW0  = (const float*)d_in[2];
  const float* nvp_b0 = (const float*)d_in[3];
  const float* nvpW1  = (const float*)d_in[4];
  const float* nvp_b1 = (const float*)d_in[5];
  const float* nvpW2  = (const float*)d_in[6];
  const float* nvp_b2 = (const float*)d_in[7];
  const float* odeW0  = (const float*)d_in[8];
  const float* ode_b0 = (const float*)d_in[9];
  const float* odeW1  = (const float*)d_in[10];
  const float* ode_b1 = (const float*)d_in[11];
  const float* odeW2  = (const float*)d_in[12];
  const float* ode_b2 = (const float*)d_in[13];
  const float* bn1m   = (const float*)d_in[14];
  const float* bn1v   = (const float*)d_in[15];
  const float* bn1g   = (const float*)d_in[16];
  const float* bn1b   = (const float*)d_in[17];
  const float* bn2m   = (const float*)d_in[18];
  const float* bn2v   = (const float*)d_in[19];
  const float* bn2g   = (const float*)d_in[20];
  const float* bn2b   = (const float*)d_in[21];
  unsigned short* ws  = (unsigned short*)d_ws;
  float* out          = (float*)d_out;

  int pblocks = (WS_ELEMS + 255) / 256;
  prep_kernel<<<pblocks, 256, 0, stream>>>(odeW0, odeW1, odeW2, nvpW0, nvpW1, nvpW2, ws);
  flow_kernel<<<256, 512, 0, stream>>>(x, nvp_b0, nvp_b1, nvp_b2, odeW0,
                                       ode_b0, ode_b1, ode_b2,
                                       bn1m, bn1v, bn1g, bn1b,
                                       bn2m, bn2v, bn2g, bn2b,
                                       ws, out);
}

// Round 9
// 1506.061 us; speedup vs baseline: 2.4177x; 1.4914x over previous
//
#include <hip/hip_runtime.h>

// StackedFlow v8: W1-in-LDS, 32-row tile — fit register demand under the immovable cap.
// r3-r8: allocator budget = 65536/blockDim VGPRs (512->128) regardless of launch_bounds /
// waves_per_eu / static LDS / amdgpu_num_vgpr; weights-in-VGPR always spills (~82MB scratch
// stores, WRITE_SIZE 91MB). v8: W1 fragments in a 128KB LDS buffer (staged 2x/layer; A-frag
// ds_read_b128 stride-16B conflict-free), W0/W2 slices in regs (16+32). 32-row tile, 1024
// blocks x 512 thr (8 waves). Demand ~113 < 128 -> no spill by construction.
// ys buffer dropped: recombine reads x0 from yin (bf16 pass-through; margin OK vs 0.32).

#define LNUM   4
#define NSTEP  8
#define EPSV   1e-3f

typedef __attribute__((ext_vector_type(8))) short  short8;
typedef __attribute__((ext_vector_type(4))) float  floatx4;

#define MF(a, b, c) __builtin_amdgcn_mfma_f32_16x16x32_bf16((a), (b), (c), 0, 0, 0)

// d_ws layout (bf16 element offsets), per-GEMM fragment arrays [layer][nt*KS+ks][lane][8]
#define OW0_OFF 0        // ode W0 rows 1..64  (64 x 256)
#define OW1_OFF 65536    // ode W1            (256 x 256)
#define OW2_OFF 327680   // ode W2            (256 x 64)
#define NW0_OFF 393216   // nvp W0            (32 x 256)
#define NW1_OFF 425984   // nvp W1            (256 x 256)
#define NW2_OFF 688128   // nvp W2            (256 x 64)
#define WS_ELEMS 753664

// LDS byte offsets
#define W1B_OFF  0        // 128K: W1 fragments short8[8192], idx (ntg*8+ks)*64+lane
#define H1_OFF   131072   // 16K bf16 [32][256] RS=512 swz((m&15)<<4)
#define YIN_OFF  147456   // 4K  bf16 [32][64]  RS=128 swz((m&7)<<4)   (x0 in NVP phase)
#define X1B_OFF  151552   // 2K  bf16 [32][32]  RS=64  swz((m&3)<<4)
#define SHF_OFF  153600   // 2K  bf16 [32][32]  RS=64  swz((m&3)<<4)
#define PARS_OFF 155648   // 3328B: b0 | b1(+256) | b2(+512) | w0row0(+576)
#define LDS_SIZE 158976

__device__ __forceinline__ unsigned short f2bfu(float f) {
  unsigned int u = __float_as_uint(f);
  return (unsigned short)((u + 0x7FFFu + ((u >> 16) & 1u)) >> 16);  // RNE
}

__device__ __forceinline__ unsigned long long pack4bf(float a, float b, float c, float d) {
  return (unsigned long long)f2bfu(a)
       | ((unsigned long long)f2bfu(b) << 16)
       | ((unsigned long long)f2bfu(c) << 32)
       | ((unsigned long long)f2bfu(d) << 48);
}

__device__ __forceinline__ float bfu2f(unsigned short u) {
  return __uint_as_float((unsigned int)u << 16);
}

__device__ __forceinline__ float tanh_fast(float x) {
  float e = __expf(2.0f * x);
  return 1.0f - 2.0f * __builtin_amdgcn_rcpf(e + 1.0f);
}

// ---------------- weight prep: fp32 [K][N] -> bf16 A-fragment order (unchanged) ----------------
__global__ void prep_kernel(const float* __restrict__ odeW0, const float* __restrict__ odeW1,
                            const float* __restrict__ odeW2, const float* __restrict__ nvpW0,
                            const float* __restrict__ nvpW1, const float* __restrict__ nvpW2,
                            unsigned short* __restrict__ ws) {
  int idx = blockIdx.x * blockDim.x + threadIdx.x;
  if (idx >= WS_ELEMS) return;
  const float* W; int base, K, N, lstride, skip;
  int f = idx;
  if (f < OW1_OFF)      { W = odeW0; base = OW0_OFF; K = 64;  N = 256; lstride = 16640; skip = 1; f -= OW0_OFF; }
  else if (f < OW2_OFF) { W = odeW1; base = OW1_OFF; K = 256; N = 256; lstride = 65536; skip = 0; f -= OW1_OFF; }
  else if (f < NW0_OFF) { W = odeW2; base = OW2_OFF; K = 256; N = 64;  lstride = 16384; skip = 0; f -= OW2_OFF; }
  else if (f < NW1_OFF) { W = nvpW0; base = NW0_OFF; K = 32;  N = 256; lstride = 8192;  skip = 0; f -= NW0_OFF; }
  else if (f < NW2_OFF) { W = nvpW1; base = NW1_OFF; K = 256; N = 256; lstride = 65536; skip = 0; f -= NW1_OFF; }
  else                  { W = nvpW2; base = NW2_OFF; K = 256; N = 64;  lstride = 16384; skip = 0; f -= NW2_OFF; }
  int per   = K * N;
  int layer = f / per;
  int e     = f - layer * per;
  int j  = e & 7;
  int l  = (e >> 3) & 63;
  int t  = e >> 9;                 // nt*KS + ks
  int KS = K >> 5; if (KS < 1) KS = 1;
  int ks = t % KS;
  int nt = t / KS;
  int n = nt * 16 + (l & 15);
  int k = ks * 32 + ((l >> 4) << 3) + j;
  ws[base + layer * per + e] = f2bfu(W[layer * lstride + (k + skip) * N + n]);
}

// store 4 consecutive n of batch-row m as bf16 into h1 [m][256], swz (m&15)<<4
__device__ __forceinline__ void st_h(char* dst, int m, int n0, float a, float b, float c, float d) {
  int off = (m * 512 + n0 * 2) ^ ((m & 15) << 4);
  *reinterpret_cast<unsigned long long*>(dst + off) = pack4bf(a, b, c, d);
}

// ---------------- fused flow kernel: 1024 blocks x 512 threads, 32 rows/block ----------------
__global__ void
__launch_bounds__(512)
flow_kernel(const float* __restrict__ xin,
            const float* __restrict__ nvp_b0, const float* __restrict__ nvp_b1,
            const float* __restrict__ nvp_b2,
            const float* __restrict__ odeW0_full,
            const float* __restrict__ ode_b0, const float* __restrict__ ode_b1,
            const float* __restrict__ ode_b2,
            const float* __restrict__ bn1m, const float* __restrict__ bn1v,
            const float* __restrict__ bn1g, const float* __restrict__ bn1b,
            const float* __restrict__ bn2m, const float* __restrict__ bn2v,
            const float* __restrict__ bn2g, const float* __restrict__ bn2b,
            const unsigned short* __restrict__ ws,
            float* __restrict__ out) {
  __shared__ __align__(16) char smem[LDS_SIZE];
  short8* w1b = reinterpret_cast<short8*>(smem + W1B_OFF);
  char*  h1   = smem + H1_OFF;
  char*  yinb = smem + YIN_OFF;
  char*  x1b  = smem + X1B_OFF;
  char*  shfb = smem + SHF_OFF;
  float* pars = reinterpret_cast<float*>(smem + PARS_OFF);

  const floatx4 zero4 = {0.f, 0.f, 0.f, 0.f};

  const int tid  = threadIdx.x;
  const int lane = tid & 63;
  const int w    = tid >> 6;        // wave 0..7
  const int l15  = lane & 15;
  const int g    = lane >> 4;
  const int wn   = w & 3;           // y/G3 dim-slice (16 of 64)
  const int wm   = w >> 2;          // y/G3 row-half (16 of 32)
  const int nb   = w * 32;          // G1/G2 n-slice base (32 of 256)
  const int mrow = wm * 16 + l15;   // this thread's local row (0..31)
  const int row0 = blockIdx.x * 32;
  const int d0   = wn * 16 + g * 4; // this thread's dim base
  const float dtv = 1.0f / NSTEP;

  float y[4];   // y[p] at row (row0+mrow), dim (d0+p)
  {
    floatx4 v = *reinterpret_cast<const floatx4*>(xin + (row0 + mrow) * 64 + d0);
    y[0] = v[0]; y[1] = v[1]; y[2] = v[2]; y[3] = v[3];
  }

  short8 aw0[2][2];   // W0 slice: [nt][ks] (NVP: ks=0 only)
  short8 aw2[8];      // W2 slice: n-slice 16 (wn), 8 ks

  for (int l = 0; l < LNUM; ++l) {
    __syncthreads();                       // B0: prev-layer LDS readers done
    {                                      // stage NVP W1 -> w1b
      const short8* src = reinterpret_cast<const short8*>(ws + NW1_OFF + l * 65536);
      #pragma unroll 4
      for (int i = tid; i < 8192; i += 512) w1b[i] = src[i];
    }
    if (wn >= 2) {                         // stash x0 (dims 32..63) bf16 -> yin
      int off = (mrow * 128 + (d0 - 32) * 2) ^ ((mrow & 7) << 4);
      *reinterpret_cast<unsigned long long*>(yinb + off) = pack4bf(y[0], y[1], y[2], y[3]);
    } else {                               // stash x1 (dims 0..31) bf16 -> x1b
      int off = (mrow * 64 + d0 * 2) ^ ((mrow & 3) << 4);
      *reinterpret_cast<unsigned long long*>(x1b + off) = pack4bf(y[0], y[1], y[2], y[3]);
    }
    for (int i = tid; i < 576; i += 512) { // NVP biases
      float v;
      if (i < 256)      v = nvp_b0[l * 256 + i];
      else if (i < 512) v = nvp_b1[l * 256 + i - 256];
      else              v = nvp_b2[l * 64 + i - 512];
      pars[i] = v;
    }
    {                                      // NVP W0 + W2 slices -> regs
      const short8* p0 = reinterpret_cast<const short8*>(ws + NW0_OFF + l * 8192);
      const short8* p2 = reinterpret_cast<const short8*>(ws + NW2_OFF + l * 16384);
      aw0[0][0] = p0[(w * 2 + 0) * 64 + lane];
      aw0[1][0] = p0[(w * 2 + 1) * 64 + lane];
      #pragma unroll
      for (int ks = 0; ks < 8; ++ks) aw2[ks] = p2[(wn * 8 + ks) * 64 + lane];
    }
    __syncthreads();                       // B1

    // ---- NVP G1: h1 = relu(x0 @ W0n + b0n), K=32 ----
    {
      floatx4 acc[2][2];
      #pragma unroll
      for (int nt = 0; nt < 2; ++nt)
        #pragma unroll
        for (int mt = 0; mt < 2; ++mt) acc[nt][mt] = zero4;
      short8 B[2];
      #pragma unroll
      for (int mt = 0; mt < 2; ++mt) {
        int m = mt * 16 + l15;
        int off = (m * 128 + g * 16) ^ ((m & 7) << 4);
        B[mt] = *reinterpret_cast<const short8*>(yinb + off);
      }
      #pragma unroll
      for (int nt = 0; nt < 2; ++nt)
        #pragma unroll
        for (int mt = 0; mt < 2; ++mt) acc[nt][mt] = MF(aw0[nt][0], B[mt], acc[nt][mt]);
      #pragma unroll
      for (int nt = 0; nt < 2; ++nt) {
        int nbase = nb + nt * 16 + g * 4;
        floatx4 bb = *reinterpret_cast<const floatx4*>(pars + nbase);
        #pragma unroll
        for (int mt = 0; mt < 2; ++mt) {
          int m = mt * 16 + l15;
          st_h(h1, m, nbase,
               fmaxf(acc[nt][mt][0] + bb[0], 0.f), fmaxf(acc[nt][mt][1] + bb[1], 0.f),
               fmaxf(acc[nt][mt][2] + bb[2], 0.f), fmaxf(acc[nt][mt][3] + bb[3], 0.f));
        }
      }
    }
    __syncthreads();                       // B2

    // ---- NVP G2: relu(h1 @ W1n + b1n), in-place (A from w1b LDS) ----
    {
      floatx4 acc[2][2];
      #pragma unroll
      for (int nt = 0; nt < 2; ++nt)
        #pragma unroll
        for (int mt = 0; mt < 2; ++mt) acc[nt][mt] = zero4;
      #pragma unroll
      for (int ks = 0; ks < 8; ++ks) {
        short8 A[2], B[2];
        #pragma unroll
        for (int nt = 0; nt < 2; ++nt) A[nt] = w1b[((w * 2 + nt) * 8 + ks) * 64 + lane];
        #pragma unroll
        for (int mt = 0; mt < 2; ++mt) {
          int m = mt * 16 + l15;
          int off = (m * 512 + (ks * 32 + g * 8) * 2) ^ ((m & 15) << 4);
          B[mt] = *reinterpret_cast<const short8*>(h1 + off);
        }
        #pragma unroll
        for (int nt = 0; nt < 2; ++nt)
          #pragma unroll
          for (int mt = 0; mt < 2; ++mt) acc[nt][mt] = MF(A[nt], B[mt], acc[nt][mt]);
      }
      __syncthreads();                     // B3: all reads done
      #pragma unroll
      for (int nt = 0; nt < 2; ++nt) {
        int nbase = nb + nt * 16 + g * 4;
        floatx4 bb = *reinterpret_cast<const floatx4*>(pars + 256 + nbase);
        #pragma unroll
        for (int mt = 0; mt < 2; ++mt) {
          int m = mt * 16 + l15;
          st_h(h1, m, nbase,
               fmaxf(acc[nt][mt][0] + bb[0], 0.f), fmaxf(acc[nt][mt][1] + bb[1], 0.f),
               fmaxf(acc[nt][mt][2] + bb[2], 0.f), fmaxf(acc[nt][mt][3] + bb[3], 0.f));
        }
      }
    }
    __syncthreads();                       // B4

    // ---- NVP G3: a3 = h2 @ W2n + b2n ----
    floatx4 a3 = zero4;
    #pragma unroll
    for (int ks = 0; ks < 8; ++ks) {
      int off = (mrow * 512 + (ks * 32 + g * 8) * 2) ^ ((mrow & 15) << 4);
      short8 B = *reinterpret_cast<const short8*>(h1 + off);
      a3 = MF(aw2[ks], B, a3);
    }
    {
      floatx4 b2v = *reinterpret_cast<const floatx4*>(pars + 512 + d0);
      #pragma unroll
      for (int p = 0; p < 4; ++p) a3[p] += b2v[p];
    }

    {                                      // stage ODE W1 -> w1b (G2 reads done at B3/B4)
      const short8* src = reinterpret_cast<const short8*>(ws + OW1_OFF + l * 65536);
      #pragma unroll 4
      for (int i = tid; i < 8192; i += 512) w1b[i] = src[i];
    }
    if (wn < 2) {                          // shift (dims 0..31) bf16 -> shf
      int off = (mrow * 64 + d0 * 2) ^ ((mrow & 3) << 4);
      *reinterpret_cast<unsigned long long*>(shfb + off) = pack4bf(a3[0], a3[1], a3[2], a3[3]);
    }
    __syncthreads();                       // B5

    // ---- recombine + BN1 ----
    if (wn < 2) {                          // new y[d<32] = x0[d] (bf16 pass-through from yin)
      int off = (mrow * 128 + d0 * 2) ^ ((mrow & 7) << 4);
      unsigned long long u = *reinterpret_cast<const unsigned long long*>(yinb + off);
      y[0] = bfu2f((unsigned short)(u));
      y[1] = bfu2f((unsigned short)(u >> 16));
      y[2] = bfu2f((unsigned short)(u >> 32));
      y[3] = bfu2f((unsigned short)(u >> 48));
    } else {                               // new y[32+j] = x1[j]*exp(ls[j]) + shift[j]
      int offx = (mrow * 64 + (d0 - 32) * 2) ^ ((mrow & 3) << 4);
      unsigned long long ux = *reinterpret_cast<const unsigned long long*>(x1b + offx);
      unsigned long long us = *reinterpret_cast<const unsigned long long*>(shfb + offx);
      y[0] = bfu2f((unsigned short)(ux)) * __expf(a3[0]) + bfu2f((unsigned short)(us));
      y[1] = bfu2f((unsigned short)(ux >> 16)) * __expf(a3[1]) + bfu2f((unsigned short)(us >> 16));
      y[2] = bfu2f((unsigned short)(ux >> 32)) * __expf(a3[2]) + bfu2f((unsigned short)(us >> 32));
      y[3] = bfu2f((unsigned short)(ux >> 48)) * __expf(a3[3]) + bfu2f((unsigned short)(us >> 48));
    }
    {
      floatx4 mm = *reinterpret_cast<const floatx4*>(bn1m + l * 64 + d0);
      floatx4 vv = *reinterpret_cast<const floatx4*>(bn1v + l * 64 + d0);
      floatx4 gg = *reinterpret_cast<const floatx4*>(bn1g + l * 64 + d0);
      floatx4 be = *reinterpret_cast<const floatx4*>(bn1b + l * 64 + d0);
      #pragma unroll
      for (int p = 0; p < 4; ++p)
        y[p] = (y[p] - be[p]) * (sqrtf(vv[p] + EPSV) / gg[p]) + mm[p];
    }

    for (int i = tid; i < 832; i += 512) { // ODE biases + t-row
      float v;
      if (i < 256)      v = ode_b0[l * 256 + i];
      else if (i < 512) v = ode_b1[l * 256 + i - 256];
      else if (i < 576) v = ode_b2[l * 64 + i - 512];
      else              v = odeW0_full[l * 16640 + i - 576];
      pars[i] = v;
    }
    {                                      // ODE W0 + W2 slices -> regs
      const short8* p0 = reinterpret_cast<const short8*>(ws + OW0_OFF + l * 16384);
      const short8* p2 = reinterpret_cast<const short8*>(ws + OW2_OFF + l * 16384);
      #pragma unroll
      for (int nt = 0; nt < 2; ++nt)
        #pragma unroll
        for (int ks = 0; ks < 2; ++ks) aw0[nt][ks] = p0[((w * 2 + nt) * 2 + ks) * 64 + lane];
      #pragma unroll
      for (int ks = 0; ks < 8; ++ks) aw2[ks] = p2[(wn * 8 + ks) * 64 + lane];
    }
    __syncthreads();                       // B6: recombine reads done; staging/pars done

    // ================= FFJORD: 8 RK4 steps =================
    float ka[4], kc[4];
    for (int s = 0; s < NSTEP; ++s) {
      float t0 = (float)s * dtv;
      for (int stg = 0; stg < 4; ++stg) {
        float cadd = (stg == 0) ? 0.0f : ((stg == 3) ? dtv : 0.5f * dtv);
        float tcur = t0 + cadd;
        {                                  // yin = y (+ cadd*k_prev), bf16 [32][64]
          float v0, v1, v2, v3;
          if (stg == 0) { v0 = y[0]; v1 = y[1]; v2 = y[2]; v3 = y[3]; }
          else {
            v0 = fmaf(cadd, kc[0], y[0]); v1 = fmaf(cadd, kc[1], y[1]);
            v2 = fmaf(cadd, kc[2], y[2]); v3 = fmaf(cadd, kc[3], y[3]);
          }
          int off = (mrow * 128 + d0 * 2) ^ ((mrow & 7) << 4);
          *reinterpret_cast<unsigned long long*>(yinb + off) = pack4bf(v0, v1, v2, v3);
        }
        __syncthreads();                   // (a): yin ready; prev G3 h1-reads done

        // G1: h1 = tanh(yin @ W0o + b0o + tcur*w0row0), K=64
        {
          floatx4 acc[2][2];
          #pragma unroll
          for (int nt = 0; nt < 2; ++nt)
            #pragma unroll
            for (int mt = 0; mt < 2; ++mt) acc[nt][mt] = zero4;
          #pragma unroll
          for (int ks = 0; ks < 2; ++ks) {
            short8 B[2];
            #pragma unroll
            for (int mt = 0; mt < 2; ++mt) {
              int m = mt * 16 + l15;
              int off = (m * 128 + (ks * 32 + g * 8) * 2) ^ ((m & 7) << 4);
              B[mt] = *reinterpret_cast<const short8*>(yinb + off);
            }
            #pragma unroll
            for (int nt = 0; nt < 2; ++nt)
              #pragma unroll
              for (int mt = 0; mt < 2; ++mt) acc[nt][mt] = MF(aw0[nt][ks], B[mt], acc[nt][mt]);
          }
          #pragma unroll
          for (int nt = 0; nt < 2; ++nt) {
            int nbase = nb + nt * 16 + g * 4;
            floatx4 bb = *reinterpret_cast<const floatx4*>(pars + nbase);
            floatx4 w0 = *reinterpret_cast<const floatx4*>(pars + 576 + nbase);
            float c0 = bb[0] + tcur * w0[0], c1 = bb[1] + tcur * w0[1];
            float c2 = bb[2] + tcur * w0[2], c3 = bb[3] + tcur * w0[3];
            #pragma unroll
            for (int mt = 0; mt < 2; ++mt) {
              int m = mt * 16 + l15;
              st_h(h1, m, nbase,
                   tanh_fast(acc[nt][mt][0] + c0), tanh_fast(acc[nt][mt][1] + c1),
                   tanh_fast(acc[nt][mt][2] + c2), tanh_fast(acc[nt][mt][3] + c3));
            }
          }
        }
        __syncthreads();                   // (b)

        // G2: h2 = tanh(h1 @ W1o + b1o), in-place (A from w1b LDS)
        {
          floatx4 acc[2][2];
          #pragma unroll
          for (int nt = 0; nt < 2; ++nt)
            #pragma unroll
            for (int mt = 0; mt < 2; ++mt) acc[nt][mt] = zero4;
          #pragma unroll
          for (int ks = 0; ks < 8; ++ks) {
            short8 A[2], B[2];
            #pragma unroll
            for (int nt = 0; nt < 2; ++nt) A[nt] = w1b[((w * 2 + nt) * 8 + ks) * 64 + lane];
            #pragma unroll
            for (int mt = 0; mt < 2; ++mt) {
              int m = mt * 16 + l15;
              int off = (m * 512 + (ks * 32 + g * 8) * 2) ^ ((m & 15) << 4);
              B[mt] = *reinterpret_cast<const short8*>(h1 + off);
            }
            #pragma unroll
            for (int nt = 0; nt < 2; ++nt)
              #pragma unroll
              for (int mt = 0; mt < 2; ++mt) acc[nt][mt] = MF(A[nt], B[mt], acc[nt][mt]);
          }
          __syncthreads();                 // (c)
          #pragma unroll
          for (int nt = 0; nt < 2; ++nt) {
            int nbase = nb + nt * 16 + g * 4;
            floatx4 bb = *reinterpret_cast<const floatx4*>(pars + 256 + nbase);
            #pragma unroll
            for (int mt = 0; mt < 2; ++mt) {
              int m = mt * 16 + l15;
              st_h(h1, m, nbase,
                   tanh_fast(acc[nt][mt][0] + bb[0]), tanh_fast(acc[nt][mt][1] + bb[1]),
                   tanh_fast(acc[nt][mt][2] + bb[2]), tanh_fast(acc[nt][mt][3] + bb[3]));
            }
          }
        }
        __syncthreads();                   // (d)

        // G3: k = h2 @ W2o + b2o
        {
          floatx4 a2 = zero4;
          #pragma unroll
          for (int ks = 0; ks < 8; ++ks) {
            int off = (mrow * 512 + (ks * 32 + g * 8) * 2) ^ ((mrow & 15) << 4);
            short8 B = *reinterpret_cast<const short8*>(h1 + off);
            a2 = MF(aw2[ks], B, a2);
          }
          floatx4 b2v = *reinterpret_cast<const floatx4*>(pars + 512 + d0);
          #pragma unroll
          for (int p = 0; p < 4; ++p) kc[p] = a2[p] + b2v[p];
        }
        if (stg == 0) {
          #pragma unroll
          for (int i = 0; i < 4; ++i) ka[i] = kc[i];
        } else if (stg == 3) {
          #pragma unroll
          for (int i = 0; i < 4; ++i) ka[i] += kc[i];
        } else {
          #pragma unroll
          for (int i = 0; i < 4; ++i) ka[i] += 2.0f * kc[i];
        }
      }
      #pragma unroll
      for (int i = 0; i < 4; ++i) y[i] += (dtv / 6.0f) * ka[i];
    }

    {                                      // BN2
      floatx4 mm = *reinterpret_cast<const floatx4*>(bn2m + l * 64 + d0);
      floatx4 vv = *reinterpret_cast<const floatx4*>(bn2v + l * 64 + d0);
      floatx4 gg = *reinterpret_cast<const floatx4*>(bn2g + l * 64 + d0);
      floatx4 be = *reinterpret_cast<const floatx4*>(bn2b + l * 64 + d0);
      #pragma unroll
      for (int p = 0; p < 4; ++p)
        y[p] = (y[p] - be[p]) * (sqrtf(vv[p] + EPSV) / gg[p]) + mm[p];
    }
  }

  {
    floatx4 v = {y[0], y[1], y[2], y[3]};
    *reinterpret_cast<floatx4*>(out + (row0 + mrow) * 64 + d0) = v;
  }
}

extern "C" void kernel_launch(void* const* d_in, const int* in_sizes, int n_in,
                              void* d_out, int out_size, void* d_ws, size_t ws_size,
                              hipStream_t stream) {
  const float* x      = (const float*)d_in[0];
  const float* nvpW0  = (const float*)d_in[2];
  const float* nvp_b0 = (const float*)d_in[3];
  const float* nvpW1  = (const float*)d_in[4];
  const float* nvp_b1 = (const float*)d_in[5];
  const float* nvpW2  = (const float*)d_in[6];
  const float* nvp_b2 = (const float*)d_in[7];
  const float* odeW0  = (const float*)d_in[8];
  const float* ode_b0 = (const float*)d_in[9];
  const float* odeW1  = (const float*)d_in[10];
  const float* ode_b1 = (const float*)d_in[11];
  const float* odeW2  = (const float*)d_in[12];
  const float* ode_b2 = (const float*)d_in[13];
  const float* bn1m   = (const float*)d_in[14];
  const float* bn1v   = (const float*)d_in[15];
  const float* bn1g   = (const float*)d_in[16];
  const float* bn1b   = (const float*)d_in[17];
  const float* bn2m   = (const float*)d_in[18];
  const float* bn2v   = (const float*)d_in[19];
  const float* bn2g   = (const float*)d_in[20];
  const float* bn2b   = (const float*)d_in[21];
  unsigned short* ws  = (unsigned short*)d_ws;
  float* out          = (float*)d_out;

  int pblocks = (WS_ELEMS + 255) / 256;
  prep_kernel<<<pblocks, 256, 0, stream>>>(odeW0, odeW1, odeW2, nvpW0, nvpW1, nvpW2, ws);
  flow_kernel<<<1024, 512, 0, stream>>>(x, nvp_b0, nvp_b1, nvp_b2, odeW0,
                                        ode_b0, ode_b1, ode_b2,
                                        bn1m, bn1v, bn1g, bn1b,
                                        bn2m, bn2v, bn2g, bn2b,
                                        ws, out);
}

// Round 10
// 1326.260 us; speedup vs baseline: 2.7455x; 1.1356x over previous
//
#include <hip/hip_runtime.h>

// StackedFlow v9 = v8 + {3-barriers/eval, W1-ks0-2-in-regs, cheap bf16 pack}.
// r9: spills eliminated (VGPR 96, WRITE 8KB), 1506us. Regime: no pipe saturated
// (LDS-read ~60%, VALU 53%, MFMA 26%) -> partially barrier-bound (4/eval, lockstep).
// v9: (1) separate 16KB h2 buffer removes the in-place-G2 barrier -> 3 barriers/eval;
// (2) W1 ks0-2 frags in 24 VGPRs (global-loaded per phase), w1b compact 80KB (ks3-7)
//     -> G2 A-reads 16->10/wave/eval, frees the LDS for h2 (total 126KB);
// (3) round-half-up bf16 pack (2 VALU/val vs 4). Watch: WRITE_SIZE must stay ~8KB.

#define LNUM   4
#define NSTEP  8
#define EPSV   1e-3f

typedef __attribute__((ext_vector_type(8))) short  short8;
typedef __attribute__((ext_vector_type(4))) float  floatx4;

#define MF(a, b, c) __builtin_amdgcn_mfma_f32_16x16x32_bf16((a), (b), (c), 0, 0, 0)

// d_ws layout (bf16 element offsets), per-GEMM fragment arrays [layer][nt*KS+ks][lane][8]
#define OW0_OFF 0        // ode W0 rows 1..64  (64 x 256)
#define OW1_OFF 65536    // ode W1            (256 x 256)
#define OW2_OFF 327680   // ode W2            (256 x 64)
#define NW0_OFF 393216   // nvp W0            (32 x 256)
#define NW1_OFF 425984   // nvp W1            (256 x 256)
#define NW2_OFF 688128   // nvp W2            (256 x 64)
#define WS_ELEMS 753664

// LDS byte offsets
#define W1B_OFF  0        // 80K compact: short8[5120] = [ks-3][ntg][lane]
#define H1_OFF   81920    // 16K bf16 [32][256] RS=512 swz((m&15)<<4)
#define H2_OFF   98304    // 16K bf16 [32][256] RS=512 swz((m&15)<<4)
#define YIN_OFF  114688   // 4K  bf16 [32][64]  RS=128 swz((m&7)<<4)   (x0 in NVP phase)
#define X1B_OFF  118784   // 2K  bf16 [32][32]  RS=64  swz((m&3)<<4)
#define SHF_OFF  120832   // 2K  bf16 [32][32]  RS=64  swz((m&3)<<4)
#define PARS_OFF 122880   // 3328B: b0 | b1(+256) | b2(+512) | w0row0(+576)
#define LDS_SIZE 126208

__device__ __forceinline__ unsigned short f2bfu(float f) {
  return (unsigned short)((__float_as_uint(f) + 0x8000u) >> 16);  // round-half-up
}

__device__ __forceinline__ unsigned short f2bfu_rne(float f) {
  unsigned int u = __float_as_uint(f);
  return (unsigned short)((u + 0x7FFFu + ((u >> 16) & 1u)) >> 16);  // RNE (prep only)
}

__device__ __forceinline__ unsigned long long pack4bf(float a, float b, float c, float d) {
  return (unsigned long long)f2bfu(a)
       | ((unsigned long long)f2bfu(b) << 16)
       | ((unsigned long long)f2bfu(c) << 32)
       | ((unsigned long long)f2bfu(d) << 48);
}

__device__ __forceinline__ float bfu2f(unsigned short u) {
  return __uint_as_float((unsigned int)u << 16);
}

__device__ __forceinline__ float tanh_fast(float x) {
  float e = __expf(2.0f * x);
  return 1.0f - 2.0f * __builtin_amdgcn_rcpf(e + 1.0f);
}

// ---------------- weight prep: fp32 [K][N] -> bf16 A-fragment order (unchanged) ----------------
__global__ void prep_kernel(const float* __restrict__ odeW0, const float* __restrict__ odeW1,
                            const float* __restrict__ odeW2, const float* __restrict__ nvpW0,
                            const float* __restrict__ nvpW1, const float* __restrict__ nvpW2,
                            unsigned short* __restrict__ ws) {
  int idx = blockIdx.x * blockDim.x + threadIdx.x;
  if (idx >= WS_ELEMS) return;
  const float* W; int base, K, N, lstride, skip;
  int f = idx;
  if (f < OW1_OFF)      { W = odeW0; base = OW0_OFF; K = 64;  N = 256; lstride = 16640; skip = 1; f -= OW0_OFF; }
  else if (f < OW2_OFF) { W = odeW1; base = OW1_OFF; K = 256; N = 256; lstride = 65536; skip = 0; f -= OW1_OFF; }
  else if (f < NW0_OFF) { W = odeW2; base = OW2_OFF; K = 256; N = 64;  lstride = 16384; skip = 0; f -= OW2_OFF; }
  else if (f < NW1_OFF) { W = nvpW0; base = NW0_OFF; K = 32;  N = 256; lstride = 8192;  skip = 0; f -= NW0_OFF; }
  else if (f < NW2_OFF) { W = nvpW1; base = NW1_OFF; K = 256; N = 256; lstride = 65536; skip = 0; f -= NW1_OFF; }
  else                  { W = nvpW2; base = NW2_OFF; K = 256; N = 64;  lstride = 16384; skip = 0; f -= NW2_OFF; }
  int per   = K * N;
  int layer = f / per;
  int e     = f - layer * per;
  int j  = e & 7;
  int l  = (e >> 3) & 63;
  int t  = e >> 9;                 // nt*KS + ks
  int KS = K >> 5; if (KS < 1) KS = 1;
  int ks = t % KS;
  int nt = t / KS;
  int n = nt * 16 + (l & 15);
  int k = ks * 32 + ((l >> 4) << 3) + j;
  ws[base + layer * per + e] = f2bfu_rne(W[layer * lstride + (k + skip) * N + n]);
}

// store 4 consecutive n of batch-row m as bf16 into [m][256], swz (m&15)<<4
__device__ __forceinline__ void st_h(char* dst, int m, int n0, float a, float b, float c, float d) {
  int off = (m * 512 + n0 * 2) ^ ((m & 15) << 4);
  *reinterpret_cast<unsigned long long*>(dst + off) = pack4bf(a, b, c, d);
}

// ---------------- fused flow kernel: 1024 blocks x 512 threads, 32 rows/block ----------------
__global__ void
__launch_bounds__(512)
flow_kernel(const float* __restrict__ xin,
            const float* __restrict__ nvp_b0, const float* __restrict__ nvp_b1,
            const float* __restrict__ nvp_b2,
            const float* __restrict__ odeW0_full,
            const float* __restrict__ ode_b0, const float* __restrict__ ode_b1,
            const float* __restrict__ ode_b2,
            const float* __restrict__ bn1m, const float* __restrict__ bn1v,
            const float* __restrict__ bn1g, const float* __restrict__ bn1b,
            const float* __restrict__ bn2m, const float* __restrict__ bn2v,
            const float* __restrict__ bn2g, const float* __restrict__ bn2b,
            const unsigned short* __restrict__ ws,
            float* __restrict__ out) {
  __shared__ __align__(16) char smem[LDS_SIZE];
  short8* w1b = reinterpret_cast<short8*>(smem + W1B_OFF);
  char*  h1   = smem + H1_OFF;
  char*  h2   = smem + H2_OFF;
  char*  yinb = smem + YIN_OFF;
  char*  x1b  = smem + X1B_OFF;
  char*  shfb = smem + SHF_OFF;
  float* pars = reinterpret_cast<float*>(smem + PARS_OFF);

  const floatx4 zero4 = {0.f, 0.f, 0.f, 0.f};

  const int tid  = threadIdx.x;
  const int lane = tid & 63;
  const int w    = tid >> 6;        // wave 0..7
  const int l15  = lane & 15;
  const int g    = lane >> 4;
  const int wn   = w & 3;           // y/G3 dim-slice (16 of 64)
  const int wm   = w >> 2;          // y/G3 row-half (16 of 32)
  const int nb   = w * 32;          // G1/G2 n-slice base (32 of 256)
  const int mrow = wm * 16 + l15;   // this thread's local row (0..31)
  const int row0 = blockIdx.x * 32;
  const int d0   = wn * 16 + g * 4; // this thread's dim base
  const float dtv = 1.0f / NSTEP;

  float y[4];   // y[p] at row (row0+mrow), dim (d0+p)
  {
    floatx4 v = *reinterpret_cast<const floatx4*>(xin + (row0 + mrow) * 64 + d0);
    y[0] = v[0]; y[1] = v[1]; y[2] = v[2]; y[3] = v[3];
  }

  short8 aw0[2][2];   // W0 slice: [nt][ks] (NVP: ks=0 only)
  short8 aw1h[2][3];  // W1 slice head: [nt][ks0..2] (regs; ks3..7 from w1b)
  short8 aw2[8];      // W2 slice: n-slice 16 (wn), 8 ks

  for (int l = 0; l < LNUM; ++l) {
    __syncthreads();                       // B0: prev-layer LDS readers done
    {                                      // stage NVP W1 ks3..7 -> w1b (compact)
      const short8* src = reinterpret_cast<const short8*>(ws + NW1_OFF + l * 65536);
      #pragma unroll 2
      for (int i = tid; i < 5120; i += 512) {
        int ks3 = i >> 10;
        int rem = i & 1023;
        w1b[i] = src[((rem >> 6) << 9) + ((3 + ks3) << 6) + (rem & 63)];
      }
    }
    if (wn >= 2) {                         // stash x0 (dims 32..63) bf16 -> yin
      int off = (mrow * 128 + (d0 - 32) * 2) ^ ((mrow & 7) << 4);
      *reinterpret_cast<unsigned long long*>(yinb + off) = pack4bf(y[0], y[1], y[2], y[3]);
    } else {                               // stash x1 (dims 0..31) bf16 -> x1b
      int off = (mrow * 64 + d0 * 2) ^ ((mrow & 3) << 4);
      *reinterpret_cast<unsigned long long*>(x1b + off) = pack4bf(y[0], y[1], y[2], y[3]);
    }
    for (int i = tid; i < 576; i += 512) { // NVP biases
      float v;
      if (i < 256)      v = nvp_b0[l * 256 + i];
      else if (i < 512) v = nvp_b1[l * 256 + i - 256];
      else              v = nvp_b2[l * 64 + i - 512];
      pars[i] = v;
    }
    {                                      // NVP W0 + W1-head + W2 slices -> regs
      const short8* p0 = reinterpret_cast<const short8*>(ws + NW0_OFF + l * 8192);
      const short8* p1 = reinterpret_cast<const short8*>(ws + NW1_OFF + l * 65536);
      const short8* p2 = reinterpret_cast<const short8*>(ws + NW2_OFF + l * 16384);
      aw0[0][0] = p0[(w * 2 + 0) * 64 + lane];
      aw0[1][0] = p0[(w * 2 + 1) * 64 + lane];
      #pragma unroll
      for (int nt = 0; nt < 2; ++nt)
        #pragma unroll
        for (int ks = 0; ks < 3; ++ks) aw1h[nt][ks] = p1[((w * 2 + nt) * 8 + ks) * 64 + lane];
      #pragma unroll
      for (int ks = 0; ks < 8; ++ks) aw2[ks] = p2[(wn * 8 + ks) * 64 + lane];
    }
    __syncthreads();                       // B1

    // ---- NVP G1: h1 = relu(x0 @ W0n + b0n), K=32 ----
    {
      floatx4 acc[2][2];
      #pragma unroll
      for (int nt = 0; nt < 2; ++nt)
        #pragma unroll
        for (int mt = 0; mt < 2; ++mt) acc[nt][mt] = zero4;
      short8 B[2];
      #pragma unroll
      for (int mt = 0; mt < 2; ++mt) {
        int m = mt * 16 + l15;
        int off = (m * 128 + g * 16) ^ ((m & 7) << 4);
        B[mt] = *reinterpret_cast<const short8*>(yinb + off);
      }
      #pragma unroll
      for (int nt = 0; nt < 2; ++nt)
        #pragma unroll
        for (int mt = 0; mt < 2; ++mt) acc[nt][mt] = MF(aw0[nt][0], B[mt], acc[nt][mt]);
      #pragma unroll
      for (int nt = 0; nt < 2; ++nt) {
        int nbase = nb + nt * 16 + g * 4;
        floatx4 bb = *reinterpret_cast<const floatx4*>(pars + nbase);
        #pragma unroll
        for (int mt = 0; mt < 2; ++mt) {
          int m = mt * 16 + l15;
          st_h(h1, m, nbase,
               fmaxf(acc[nt][mt][0] + bb[0], 0.f), fmaxf(acc[nt][mt][1] + bb[1], 0.f),
               fmaxf(acc[nt][mt][2] + bb[2], 0.f), fmaxf(acc[nt][mt][3] + bb[3], 0.f));
        }
      }
    }
    __syncthreads();                       // B2

    // ---- NVP G2: h2 = relu(h1 @ W1n + b1n)  (A: aw1h regs + w1b LDS) ----
    {
      floatx4 acc[2][2];
      #pragma unroll
      for (int nt = 0; nt < 2; ++nt)
        #pragma unroll
        for (int mt = 0; mt < 2; ++mt) acc[nt][mt] = zero4;
      #pragma unroll
      for (int ks = 0; ks < 8; ++ks) {
        short8 A[2], B[2];
        if (ks < 3) {
          A[0] = aw1h[0][ks]; A[1] = aw1h[1][ks];
        } else {
          A[0] = w1b[((ks - 3) << 10) + (w * 2 + 0) * 64 + lane];
          A[1] = w1b[((ks - 3) << 10) + (w * 2 + 1) * 64 + lane];
        }
        #pragma unroll
        for (int mt = 0; mt < 2; ++mt) {
          int m = mt * 16 + l15;
          int off = (m * 512 + (ks * 32 + g * 8) * 2) ^ ((m & 15) << 4);
          B[mt] = *reinterpret_cast<const short8*>(h1 + off);
        }
        #pragma unroll
        for (int nt = 0; nt < 2; ++nt)
          #pragma unroll
          for (int mt = 0; mt < 2; ++mt) acc[nt][mt] = MF(A[nt], B[mt], acc[nt][mt]);
      }
      #pragma unroll
      for (int nt = 0; nt < 2; ++nt) {
        int nbase = nb + nt * 16 + g * 4;
        floatx4 bb = *reinterpret_cast<const floatx4*>(pars + 256 + nbase);
        #pragma unroll
        for (int mt = 0; mt < 2; ++mt) {
          int m = mt * 16 + l15;
          st_h(h2, m, nbase,
               fmaxf(acc[nt][mt][0] + bb[0], 0.f), fmaxf(acc[nt][mt][1] + bb[1], 0.f),
               fmaxf(acc[nt][mt][2] + bb[2], 0.f), fmaxf(acc[nt][mt][3] + bb[3], 0.f));
        }
      }
    }
    __syncthreads();                       // B3

    // ---- NVP G3: a3 = h2 @ W2n + b2n ----
    floatx4 a3 = zero4;
    #pragma unroll
    for (int ks = 0; ks < 8; ++ks) {
      int off = (mrow * 512 + (ks * 32 + g * 8) * 2) ^ ((mrow & 15) << 4);
      short8 B = *reinterpret_cast<const short8*>(h2 + off);
      a3 = MF(aw2[ks], B, a3);
    }
    {
      floatx4 b2v = *reinterpret_cast<const floatx4*>(pars + 512 + d0);
      #pragma unroll
      for (int p = 0; p < 4; ++p) a3[p] += b2v[p];
    }

    {                                      // stage ODE W1 ks3..7 -> w1b (G2 reads done at B3)
      const short8* src = reinterpret_cast<const short8*>(ws + OW1_OFF + l * 65536);
      #pragma unroll 2
      for (int i = tid; i < 5120; i += 512) {
        int ks3 = i >> 10;
        int rem = i & 1023;
        w1b[i] = src[((rem >> 6) << 9) + ((3 + ks3) << 6) + (rem & 63)];
      }
    }
    if (wn < 2) {                          // shift (dims 0..31) bf16 -> shf
      int off = (mrow * 64 + d0 * 2) ^ ((mrow & 3) << 4);
      *reinterpret_cast<unsigned long long*>(shfb + off) = pack4bf(a3[0], a3[1], a3[2], a3[3]);
    }
    __syncthreads();                       // B5

    // ---- recombine + BN1 ----
    if (wn < 2) {                          // new y[d<32] = x0[d] (bf16 pass-through from yin)
      int off = (mrow * 128 + d0 * 2) ^ ((mrow & 7) << 4);
      unsigned long long u = *reinterpret_cast<const unsigned long long*>(yinb + off);
      y[0] = bfu2f((unsigned short)(u));
      y[1] = bfu2f((unsigned short)(u >> 16));
      y[2] = bfu2f((unsigned short)(u >> 32));
      y[3] = bfu2f((unsigned short)(u >> 48));
    } else {                               // new y[32+j] = x1[j]*exp(ls[j]) + shift[j]
      int offx = (mrow * 64 + (d0 - 32) * 2) ^ ((mrow & 3) << 4);
      unsigned long long ux = *reinterpret_cast<const unsigned long long*>(x1b + offx);
      unsigned long long us = *reinterpret_cast<const unsigned long long*>(shfb + offx);
      y[0] = bfu2f((unsigned short)(ux)) * __expf(a3[0]) + bfu2f((unsigned short)(us));
      y[1] = bfu2f((unsigned short)(ux >> 16)) * __expf(a3[1]) + bfu2f((unsigned short)(us >> 16));
      y[2] = bfu2f((unsigned short)(ux >> 32)) * __expf(a3[2]) + bfu2f((unsigned short)(us >> 32));
      y[3] = bfu2f((unsigned short)(ux >> 48)) * __expf(a3[3]) + bfu2f((unsigned short)(us >> 48));
    }
    {
      floatx4 mm = *reinterpret_cast<const floatx4*>(bn1m + l * 64 + d0);
      floatx4 vv = *reinterpret_cast<const floatx4*>(bn1v + l * 64 + d0);
      floatx4 gg = *reinterpret_cast<const floatx4*>(bn1g + l * 64 + d0);
      floatx4 be = *reinterpret_cast<const floatx4*>(bn1b + l * 64 + d0);
      #pragma unroll
      for (int p = 0; p < 4; ++p)
        y[p] = (y[p] - be[p]) * (sqrtf(vv[p] + EPSV) / gg[p]) + mm[p];
    }

    for (int i = tid; i < 832; i += 512) { // ODE biases + t-row
      float v;
      if (i < 256)      v = ode_b0[l * 256 + i];
      else if (i < 512) v = ode_b1[l * 256 + i - 256];
      else if (i < 576) v = ode_b2[l * 64 + i - 512];
      else              v = odeW0_full[l * 16640 + i - 576];
      pars[i] = v;
    }
    {                                      // ODE W0 + W1-head + W2 slices -> regs
      const short8* p0 = reinterpret_cast<const short8*>(ws + OW0_OFF + l * 16384);
      const short8* p1 = reinterpret_cast<const short8*>(ws + OW1_OFF + l * 65536);
      const short8* p2 = reinterpret_cast<const short8*>(ws + OW2_OFF + l * 16384);
      #pragma unroll
      for (int nt = 0; nt < 2; ++nt)
        #pragma unroll
        for (int ks = 0; ks < 2; ++ks) aw0[nt][ks] = p0[((w * 2 + nt) * 2 + ks) * 64 + lane];
      #pragma unroll
      for (int nt = 0; nt < 2; ++nt)
        #pragma unroll
        for (int ks = 0; ks < 3; ++ks) aw1h[nt][ks] = p1[((w * 2 + nt) * 8 + ks) * 64 + lane];
      #pragma unroll
      for (int ks = 0; ks < 8; ++ks) aw2[ks] = p2[(wn * 8 + ks) * 64 + lane];
    }
    __syncthreads();                       // B6: recombine reads done; staging/pars done

    // ================= FFJORD: 8 RK4 steps, 3 barriers/eval =================
    float ka[4], kc[4];
    for (int s = 0; s < NSTEP; ++s) {
      float t0 = (float)s * dtv;
      for (int stg = 0; stg < 4; ++stg) {
        float cadd = (stg == 0) ? 0.0f : ((stg == 3) ? dtv : 0.5f * dtv);
        float tcur = t0 + cadd;
        {                                  // yin = y (+ cadd*k_prev), bf16 [32][64]
          float v0, v1, v2, v3;
          if (stg == 0) { v0 = y[0]; v1 = y[1]; v2 = y[2]; v3 = y[3]; }
          else {
            v0 = fmaf(cadd, kc[0], y[0]); v1 = fmaf(cadd, kc[1], y[1]);
            v2 = fmaf(cadd, kc[2], y[2]); v3 = fmaf(cadd, kc[3], y[3]);
          }
          int off = (mrow * 128 + d0 * 2) ^ ((mrow & 7) << 4);
          *reinterpret_cast<unsigned long long*>(yinb + off) = pack4bf(v0, v1, v2, v3);
        }
        __syncthreads();                   // (a): yin ready; prev G2 h1-reads done

        // G1: h1 = tanh(yin @ W0o + b0o + tcur*w0row0), K=64
        {
          floatx4 acc[2][2];
          #pragma unroll
          for (int nt = 0; nt < 2; ++nt)
            #pragma unroll
            for (int mt = 0; mt < 2; ++mt) acc[nt][mt] = zero4;
          #pragma unroll
          for (int ks = 0; ks < 2; ++ks) {
            short8 B[2];
            #pragma unroll
            for (int mt = 0; mt < 2; ++mt) {
              int m = mt * 16 + l15;
              int off = (m * 128 + (ks * 32 + g * 8) * 2) ^ ((m & 7) << 4);
              B[mt] = *reinterpret_cast<const short8*>(yinb + off);
            }
            #pragma unroll
            for (int nt = 0; nt < 2; ++nt)
              #pragma unroll
              for (int mt = 0; mt < 2; ++mt) acc[nt][mt] = MF(aw0[nt][ks], B[mt], acc[nt][mt]);
          }
          #pragma unroll
          for (int nt = 0; nt < 2; ++nt) {
            int nbase = nb + nt * 16 + g * 4;
            floatx4 bb = *reinterpret_cast<const floatx4*>(pars + nbase);
            floatx4 w0 = *reinterpret_cast<const floatx4*>(pars + 576 + nbase);
            float c0 = bb[0] + tcur * w0[0], c1 = bb[1] + tcur * w0[1];
            float c2 = bb[2] + tcur * w0[2], c3 = bb[3] + tcur * w0[3];
            #pragma unroll
            for (int mt = 0; mt < 2; ++mt) {
              int m = mt * 16 + l15;
              st_h(h1, m, nbase,
                   tanh_fast(acc[nt][mt][0] + c0), tanh_fast(acc[nt][mt][1] + c1),
                   tanh_fast(acc[nt][mt][2] + c2), tanh_fast(acc[nt][mt][3] + c3));
            }
          }
        }
        __syncthreads();                   // (b)

        // G2: h2 = tanh(h1 @ W1o + b1o)  (A: aw1h regs + w1b LDS)
        {
          floatx4 acc[2][2];
          #pragma unroll
          for (int nt = 0; nt < 2; ++nt)
            #pragma unroll
            for (int mt = 0; mt < 2; ++mt) acc[nt][mt] = zero4;
          #pragma unroll
          for (int ks = 0; ks < 8; ++ks) {
            short8 A[2], B[2];
            if (ks < 3) {
              A[0] = aw1h[0][ks]; A[1] = aw1h[1][ks];
            } else {
              A[0] = w1b[((ks - 3) << 10) + (w * 2 + 0) * 64 + lane];
              A[1] = w1b[((ks - 3) << 10) + (w * 2 + 1) * 64 + lane];
            }
            #pragma unroll
            for (int mt = 0; mt < 2; ++mt) {
              int m = mt * 16 + l15;
              int off = (m * 512 + (ks * 32 + g * 8) * 2) ^ ((m & 15) << 4);
              B[mt] = *reinterpret_cast<const short8*>(h1 + off);
            }
            #pragma unroll
            for (int nt = 0; nt < 2; ++nt)
              #pragma unroll
              for (int mt = 0; mt < 2; ++mt) acc[nt][mt] = MF(A[nt], B[mt], acc[nt][mt]);
          }
          #pragma unroll
          for (int nt = 0; nt < 2; ++nt) {
            int nbase = nb + nt * 16 + g * 4;
            floatx4 bb = *reinterpret_cast<const floatx4*>(pars + 256 + nbase);
            #pragma unroll
            for (int mt = 0; mt < 2; ++mt) {
              int m = mt * 16 + l15;
              st_h(h2, m, nbase,
                   tanh_fast(acc[nt][mt][0] + bb[0]), tanh_fast(acc[nt][mt][1] + bb[1]),
                   tanh_fast(acc[nt][mt][2] + bb[2]), tanh_fast(acc[nt][mt][3] + bb[3]));
            }
          }
        }
        __syncthreads();                   // (d'): h2 ready

        // G3: k = h2 @ W2o + b2o
        {
          floatx4 a2 = zero4;
          #pragma unroll
          for (int ks = 0; ks < 8; ++ks) {
            int off = (mrow * 512 + (ks * 32 + g * 8) * 2) ^ ((mrow & 15) << 4);
            short8 B = *reinterpret_cast<const short8*>(h2 + off);
            a2 = MF(aw2[ks], B, a2);
          }
          floatx4 b2v = *reinterpret_cast<const floatx4*>(pars + 512 + d0);
          #pragma unroll
          for (int p = 0; p < 4; ++p) kc[p] = a2[p] + b2v[p];
        }
        if (stg == 0) {
          #pragma unroll
          for (int i = 0; i < 4; ++i) ka[i] = kc[i];
        } else if (stg == 3) {
          #pragma unroll
          for (int i = 0; i < 4; ++i) ka[i] += kc[i];
        } else {
          #pragma unroll
          for (int i = 0; i < 4; ++i) ka[i] += 2.0f * kc[i];
        }
      }
      #pragma unroll
      for (int i = 0; i < 4; ++i) y[i] += (dtv / 6.0f) * ka[i];
    }

    {                                      // BN2
      floatx4 mm = *reinterpret_cast<const floatx4*>(bn2m + l * 64 + d0);
      floatx4 vv = *reinterpret_cast<const floatx4*>(bn2v + l * 64 + d0);
      floatx4 gg = *reinterpret_cast<const floatx4*>(bn2g + l * 64 + d0);
      floatx4 be = *reinterpret_cast<const floatx4*>(bn2b + l * 64 + d0);
      #pragma unroll
      for (int p = 0; p < 4; ++p)
        y[p] = (y[p] - be[p]) * (sqrtf(vv[p] + EPSV) / gg[p]) + mm[p];
    }
  }

  {
    floatx4 v = {y[0], y[1], y[2], y[3]};
    *reinterpret_cast<floatx4*>(out + (row0 + mrow) * 64 + d0) = v;
  }
}

extern "C" void kernel_launch(void* const* d_in, const int* in_sizes, int n_in,
                              void* d_out, int out_size, void* d_ws, size_t ws_size,
                              hipStream_t stream) {
  const float* x      = (const float*)d_in[0];
  const float* nvpW0  = (const float*)d_in[2];
  const float* nvp_b0 = (const float*)d_in[3];
  const float* nvpW1  = (const float*)d_in[4];
  const float* nvp_b1 = (const float*)d_in[5];
  const float* nvpW2  = (const float*)d_in[6];
  const float* nvp_b2 = (const float*)d_in[7];
  const float* odeW0  = (const float*)d_in[8];
  const float* ode_b0 = (const float*)d_in[9];
  const float* odeW1  = (const float*)d_in[10];
  const float* ode_b1 = (const float*)d_in[11];
  const float* odeW2  = (const float*)d_in[12];
  const float* ode_b2 = (const float*)d_in[13];
  const float* bn1m   = (const float*)d_in[14];
  const float* bn1v   = (const float*)d_in[15];
  const float* bn1g   = (const float*)d_in[16];
  const float* bn1b   = (const float*)d_in[17];
  const float* bn2m   = (const float*)d_in[18];
  const float* bn2v   = (const float*)d_in[19];
  const float* bn2g   = (const float*)d_in[20];
  const float* bn2b   = (const float*)d_in[21];
  unsigned short* ws  = (unsigned short*)d_ws;
  float* out          = (float*)d_out;

  int pblocks = (WS_ELEMS + 255) / 256;
  prep_kernel<<<pblocks, 256, 0, stream>>>(odeW0, odeW1, odeW2, nvpW0, nvpW1, nvpW2, ws);
  flow_kernel<<<1024, 512, 0, stream>>>(x, nvp_b0, nvp_b1, nvp_b2, odeW0,
                                        ode_b0, ode_b1, ode_b2,
                                        bn1m, bn1v, bn1g, bn1b,
                                        bn2m, bn2v, bn2g, bn2b,
                                        ws, out);
}

// Round 11
// 1252.874 us; speedup vs baseline: 2.9063x; 1.0586x over previous
//
#include <hip/hip_runtime.h>
#include <hip/hip_bf16.h>

// StackedFlow v10 = v9 + {64-row tile (512 blocks), tanh-2x baked into ODE weights,
// cvt_pk bf16 pack}. r10: 1326us, VALU 56% / MFMA 24% / bank-conf 4% -> remainder is
// barrier lockstep (3/eval, 8 waves). v10 doubles work per barrier (64 rows: G1/G2 in
// 2 row-batches, acc[2][2] keeps peak ~128 VGPR) and halves staging per row. LDS 158.9KB:
// x1 folded into yin's high half-row, shf aliased into dead h1. Watch: WRITE_SIZE ~8KB
// (spill canary). tanh 2x baked at prep (odeW0/W1 x2, b0/b1/t-row x2 at staging).

#define LNUM   4
#define NSTEP  8
#define EPSV   1e-3f

typedef __attribute__((ext_vector_type(8))) short  short8;
typedef __attribute__((ext_vector_type(4))) float  floatx4;

#define MF(a, b, c) __builtin_amdgcn_mfma_f32_16x16x32_bf16((a), (b), (c), 0, 0, 0)

// d_ws layout (bf16 element offsets), per-GEMM fragment arrays [layer][nt*KS+ks][lane][8]
#define OW0_OFF 0        // ode W0 rows 1..64  (64 x 256)  PRE-SCALED x2
#define OW1_OFF 65536    // ode W1            (256 x 256)  PRE-SCALED x2
#define OW2_OFF 327680   // ode W2            (256 x 64)
#define NW0_OFF 393216   // nvp W0            (32 x 256)
#define NW1_OFF 425984   // nvp W1            (256 x 256)
#define NW2_OFF 688128   // nvp W2            (256 x 64)
#define WS_ELEMS 753664

// LDS byte offsets (64-row tile)
#define W1B_OFF  0        // 80K compact: short8[5120] = [ks-3][ntg][lane]
#define H1_OFF   81920    // 32K bf16 [64][256] RS=512 swz((m&15)<<4); first 4K aliases shf
#define H2_OFF   114688   // 32K bf16 [64][256] RS=512 swz((m&15)<<4)
#define YIN_OFF  147456   // 8K  bf16 [64][64]  RS=128 swz((m&7)<<4); NVP: x0 lo-half, x1 hi-half
#define PARS_OFF 155648   // 3328B: b0 | b1(+256) | b2(+512) | w0row0(+576)
#define LDS_SIZE 158976

__device__ __forceinline__ unsigned short f2bfu_rne(float f) {
  unsigned int u = __float_as_uint(f);
  return (unsigned short)((u + 0x7FFFu + ((u >> 16) & 1u)) >> 16);  // RNE (prep only)
}

__device__ __forceinline__ unsigned long long pack4bf(float a, float b, float c, float d) {
  __hip_bfloat162 lo = __float22bfloat162_rn(make_float2(a, b));
  __hip_bfloat162 hi = __float22bfloat162_rn(make_float2(c, d));
  unsigned int ul, uh;
  __builtin_memcpy(&ul, &lo, 4);
  __builtin_memcpy(&uh, &hi, 4);
  return (unsigned long long)ul | ((unsigned long long)uh << 32);
}

__device__ __forceinline__ float bfu2f(unsigned short u) {
  return __uint_as_float((unsigned int)u << 16);
}

// input v is ALREADY 2x the mathematical pre-activation (weights pre-scaled)
__device__ __forceinline__ float tanh_fast2(float v) {
  float e = __expf(v);
  return 1.0f - 2.0f * __builtin_amdgcn_rcpf(e + 1.0f);
}

// ---------------- weight prep: fp32 [K][N] -> bf16 A-fragment order ----------------
__global__ void prep_kernel(const float* __restrict__ odeW0, const float* __restrict__ odeW1,
                            const float* __restrict__ odeW2, const float* __restrict__ nvpW0,
                            const float* __restrict__ nvpW1, const float* __restrict__ nvpW2,
                            unsigned short* __restrict__ ws) {
  int idx = blockIdx.x * blockDim.x + threadIdx.x;
  if (idx >= WS_ELEMS) return;
  const float* W; int base, K, N, lstride, skip; float scale;
  int f = idx;
  if (f < OW1_OFF)      { W = odeW0; base = OW0_OFF; K = 64;  N = 256; lstride = 16640; skip = 1; scale = 2.f; f -= OW0_OFF; }
  else if (f < OW2_OFF) { W = odeW1; base = OW1_OFF; K = 256; N = 256; lstride = 65536; skip = 0; scale = 2.f; f -= OW1_OFF; }
  else if (f < NW0_OFF) { W = odeW2; base = OW2_OFF; K = 256; N = 64;  lstride = 16384; skip = 0; scale = 1.f; f -= OW2_OFF; }
  else if (f < NW1_OFF) { W = nvpW0; base = NW0_OFF; K = 32;  N = 256; lstride = 8192;  skip = 0; scale = 1.f; f -= NW0_OFF; }
  else if (f < NW2_OFF) { W = nvpW1; base = NW1_OFF; K = 256; N = 256; lstride = 65536; skip = 0; scale = 1.f; f -= NW1_OFF; }
  else                  { W = nvpW2; base = NW2_OFF; K = 256; N = 64;  lstride = 16384; skip = 0; scale = 1.f; f -= NW2_OFF; }
  int per   = K * N;
  int layer = f / per;
  int e     = f - layer * per;
  int j  = e & 7;
  int l  = (e >> 3) & 63;
  int t  = e >> 9;                 // nt*KS + ks
  int KS = K >> 5; if (KS < 1) KS = 1;
  int ks = t % KS;
  int nt = t / KS;
  int n = nt * 16 + (l & 15);
  int k = ks * 32 + ((l >> 4) << 3) + j;
  ws[base + layer * per + e] = f2bfu_rne(scale * W[layer * lstride + (k + skip) * N + n]);
}

// store 4 consecutive n of batch-row m as bf16 into [m][256], swz (m&15)<<4
__device__ __forceinline__ void st_h(char* dst, int m, int n0, float a, float b, float c, float d) {
  int off = (m * 512 + n0 * 2) ^ ((m & 15) << 4);
  *reinterpret_cast<unsigned long long*>(dst + off) = pack4bf(a, b, c, d);
}

// ---------------- fused flow kernel: 512 blocks x 512 threads, 64 rows/block ----------------
__global__ void
__launch_bounds__(512)
flow_kernel(const float* __restrict__ xin,
            const float* __restrict__ nvp_b0, const float* __restrict__ nvp_b1,
            const float* __restrict__ nvp_b2,
            const float* __restrict__ odeW0_full,
            const float* __restrict__ ode_b0, const float* __restrict__ ode_b1,
            const float* __restrict__ ode_b2,
            const float* __restrict__ bn1m, const float* __restrict__ bn1v,
            const float* __restrict__ bn1g, const float* __restrict__ bn1b,
            const float* __restrict__ bn2m, const float* __restrict__ bn2v,
            const float* __restrict__ bn2g, const float* __restrict__ bn2b,
            const unsigned short* __restrict__ ws,
            float* __restrict__ out) {
  __shared__ __align__(16) char smem[LDS_SIZE];
  short8* w1b = reinterpret_cast<short8*>(smem + W1B_OFF);
  char*  h1   = smem + H1_OFF;
  char*  h2   = smem + H2_OFF;
  char*  yinb = smem + YIN_OFF;
  char*  shfb = smem + H1_OFF;       // alias: shf [64][32]bf16 lives in dead h1 space
  float* pars = reinterpret_cast<float*>(smem + PARS_OFF);

  const floatx4 zero4 = {0.f, 0.f, 0.f, 0.f};

  const int tid  = threadIdx.x;
  const int lane = tid & 63;
  const int w    = tid >> 6;        // wave 0..7
  const int l15  = lane & 15;
  const int g    = lane >> 4;
  const int wn   = w & 3;           // y/G3 dim-slice (16 of 64)
  const int wm   = w >> 2;          // y/G3 row-half (32 of 64)
  const int nb   = w * 32;          // G1/G2 n-slice base (32 of 256)
  const int row0 = blockIdx.x * 64;
  const int d0   = wn * 16 + g * 4; // this thread's dim base
  const float dtv = 1.0f / NSTEP;

  float y[8];   // y[mt*4+p] at local row (wm*32 + mt*16 + l15), dim (d0+p)
  #pragma unroll
  for (int mt = 0; mt < 2; ++mt) {
    int m = wm * 32 + mt * 16 + l15;
    floatx4 v = *reinterpret_cast<const floatx4*>(xin + (row0 + m) * 64 + d0);
    y[mt * 4 + 0] = v[0]; y[mt * 4 + 1] = v[1]; y[mt * 4 + 2] = v[2]; y[mt * 4 + 3] = v[3];
  }

  short8 aw0[2][2];   // W0 slice: [nt][ks] (NVP: ks=0 only)
  short8 aw1h[2][3];  // W1 slice head: [nt][ks0..2] (regs; ks3..7 from w1b)
  short8 aw2[8];      // W2 slice: n-slice 16 (wn), 8 ks

  for (int l = 0; l < LNUM; ++l) {
    __syncthreads();                       // B0: prev-layer LDS readers done
    {                                      // stage NVP W1 ks3..7 -> w1b (compact)
      const short8* src = reinterpret_cast<const short8*>(ws + NW1_OFF + l * 65536);
      #pragma unroll 2
      for (int i = tid; i < 5120; i += 512) {
        int ks3 = i >> 10;
        int rem = i & 1023;
        w1b[i] = src[((rem >> 6) << 9) + ((3 + ks3) << 6) + (rem & 63)];
      }
    }
    #pragma unroll
    for (int mt = 0; mt < 2; ++mt) {       // stash x halves into yin
      int m = wm * 32 + mt * 16 + l15;
      if (wn >= 2) {                       // x0 (dims 32..63) -> low half-row
        int off = (m * 128 + (d0 - 32) * 2) ^ ((m & 7) << 4);
        *reinterpret_cast<unsigned long long*>(yinb + off) =
            pack4bf(y[mt * 4 + 0], y[mt * 4 + 1], y[mt * 4 + 2], y[mt * 4 + 3]);
      } else {                             // x1 (dims 0..31) -> high half-row
        int off = (m * 128 + 64 + d0 * 2) ^ ((m & 7) << 4);
        *reinterpret_cast<unsigned long long*>(yinb + off) =
            pack4bf(y[mt * 4 + 0], y[mt * 4 + 1], y[mt * 4 + 2], y[mt * 4 + 3]);
      }
    }
    for (int i = tid; i < 576; i += 512) { // NVP biases
      float v;
      if (i < 256)      v = nvp_b0[l * 256 + i];
      else if (i < 512) v = nvp_b1[l * 256 + i - 256];
      else              v = nvp_b2[l * 64 + i - 512];
      pars[i] = v;
    }
    {                                      // NVP W0 + W1-head + W2 slices -> regs
      const short8* p0 = reinterpret_cast<const short8*>(ws + NW0_OFF + l * 8192);
      const short8* p1 = reinterpret_cast<const short8*>(ws + NW1_OFF + l * 65536);
      const short8* p2 = reinterpret_cast<const short8*>(ws + NW2_OFF + l * 16384);
      aw0[0][0] = p0[(w * 2 + 0) * 64 + lane];
      aw0[1][0] = p0[(w * 2 + 1) * 64 + lane];
      #pragma unroll
      for (int nt = 0; nt < 2; ++nt)
        #pragma unroll
        for (int ks = 0; ks < 3; ++ks) aw1h[nt][ks] = p1[((w * 2 + nt) * 8 + ks) * 64 + lane];
      #pragma unroll
      for (int ks = 0; ks < 8; ++ks) aw2[ks] = p2[(wn * 8 + ks) * 64 + lane];
    }
    __syncthreads();                       // B1

    // ---- NVP G1: h1 = relu(x0 @ W0n + b0n), K=32, 64 rows in 2 batches ----
    #pragma unroll
    for (int mh = 0; mh < 2; ++mh) {
      floatx4 acc[2][2];
      #pragma unroll
      for (int nt = 0; nt < 2; ++nt)
        #pragma unroll
        for (int mt = 0; mt < 2; ++mt) acc[nt][mt] = zero4;
      short8 B[2];
      #pragma unroll
      for (int mt = 0; mt < 2; ++mt) {
        int m = mh * 32 + mt * 16 + l15;
        int off = (m * 128 + g * 16) ^ ((m & 7) << 4);
        B[mt] = *reinterpret_cast<const short8*>(yinb + off);
      }
      #pragma unroll
      for (int nt = 0; nt < 2; ++nt)
        #pragma unroll
        for (int mt = 0; mt < 2; ++mt) acc[nt][mt] = MF(aw0[nt][0], B[mt], acc[nt][mt]);
      #pragma unroll
      for (int nt = 0; nt < 2; ++nt) {
        int nbase = nb + nt * 16 + g * 4;
        floatx4 bb = *reinterpret_cast<const floatx4*>(pars + nbase);
        #pragma unroll
        for (int mt = 0; mt < 2; ++mt) {
          int m = mh * 32 + mt * 16 + l15;
          st_h(h1, m, nbase,
               fmaxf(acc[nt][mt][0] + bb[0], 0.f), fmaxf(acc[nt][mt][1] + bb[1], 0.f),
               fmaxf(acc[nt][mt][2] + bb[2], 0.f), fmaxf(acc[nt][mt][3] + bb[3], 0.f));
        }
      }
    }
    __syncthreads();                       // B2

    // ---- NVP G2: h2 = relu(h1 @ W1n + b1n), 64 rows in 2 batches ----
    #pragma unroll
    for (int mh = 0; mh < 2; ++mh) {
      floatx4 acc[2][2];
      #pragma unroll
      for (int nt = 0; nt < 2; ++nt)
        #pragma unroll
        for (int mt = 0; mt < 2; ++mt) acc[nt][mt] = zero4;
      #pragma unroll
      for (int ks = 0; ks < 8; ++ks) {
        short8 A[2], B[2];
        if (ks < 3) {
          A[0] = aw1h[0][ks]; A[1] = aw1h[1][ks];
        } else {
          A[0] = w1b[((ks - 3) << 10) + (w * 2 + 0) * 64 + lane];
          A[1] = w1b[((ks - 3) << 10) + (w * 2 + 1) * 64 + lane];
        }
        #pragma unroll
        for (int mt = 0; mt < 2; ++mt) {
          int m = mh * 32 + mt * 16 + l15;
          int off = (m * 512 + (ks * 32 + g * 8) * 2) ^ ((m & 15) << 4);
          B[mt] = *reinterpret_cast<const short8*>(h1 + off);
        }
        #pragma unroll
        for (int nt = 0; nt < 2; ++nt)
          #pragma unroll
          for (int mt = 0; mt < 2; ++mt) acc[nt][mt] = MF(A[nt], B[mt], acc[nt][mt]);
      }
      #pragma unroll
      for (int nt = 0; nt < 2; ++nt) {
        int nbase = nb + nt * 16 + g * 4;
        floatx4 bb = *reinterpret_cast<const floatx4*>(pars + 256 + nbase);
        #pragma unroll
        for (int mt = 0; mt < 2; ++mt) {
          int m = mh * 32 + mt * 16 + l15;
          st_h(h2, m, nbase,
               fmaxf(acc[nt][mt][0] + bb[0], 0.f), fmaxf(acc[nt][mt][1] + bb[1], 0.f),
               fmaxf(acc[nt][mt][2] + bb[2], 0.f), fmaxf(acc[nt][mt][3] + bb[3], 0.f));
        }
      }
    }
    __syncthreads();                       // B3: G2 h1/w1b reads done, h2 ready

    // ---- NVP G3: a3 = h2 @ W2n + b2n (own rows) ----
    floatx4 a3[2];
    a3[0] = zero4; a3[1] = zero4;
    #pragma unroll
    for (int ks = 0; ks < 8; ++ks) {
      #pragma unroll
      for (int mt = 0; mt < 2; ++mt) {
        int m = wm * 32 + mt * 16 + l15;
        int off = (m * 512 + (ks * 32 + g * 8) * 2) ^ ((m & 15) << 4);
        short8 B = *reinterpret_cast<const short8*>(h2 + off);
        a3[mt] = MF(aw2[ks], B, a3[mt]);
      }
    }
    {
      floatx4 b2v = *reinterpret_cast<const floatx4*>(pars + 512 + d0);
      #pragma unroll
      for (int mt = 0; mt < 2; ++mt)
        #pragma unroll
        for (int p = 0; p < 4; ++p) a3[mt][p] += b2v[p];
    }

    {                                      // stage ODE W1 ks3..7 -> w1b (reads done at B3)
      const short8* src = reinterpret_cast<const short8*>(ws + OW1_OFF + l * 65536);
      #pragma unroll 2
      for (int i = tid; i < 5120; i += 512) {
        int ks3 = i >> 10;
        int rem = i & 1023;
        w1b[i] = src[((rem >> 6) << 9) + ((3 + ks3) << 6) + (rem & 63)];
      }
    }
    if (wn < 2) {                          // shift (dims 0..31) bf16 -> shf (h1 alias; safe after B3)
      #pragma unroll
      for (int mt = 0; mt < 2; ++mt) {
        int m = wm * 32 + mt * 16 + l15;
        int off = (m * 64 + d0 * 2) ^ ((m & 3) << 4);
        *reinterpret_cast<unsigned long long*>(shfb + off) =
            pack4bf(a3[mt][0], a3[mt][1], a3[mt][2], a3[mt][3]);
      }
    }
    __syncthreads();                       // B5

    // ---- recombine + BN1 ----
    #pragma unroll
    for (int mt = 0; mt < 2; ++mt) {
      int m = wm * 32 + mt * 16 + l15;
      if (wn < 2) {                        // new y[d<32] = x0[d] (pass-through from yin low)
        int off = (m * 128 + d0 * 2) ^ ((m & 7) << 4);
        unsigned long long u = *reinterpret_cast<const unsigned long long*>(yinb + off);
        y[mt * 4 + 0] = bfu2f((unsigned short)(u));
        y[mt * 4 + 1] = bfu2f((unsigned short)(u >> 16));
        y[mt * 4 + 2] = bfu2f((unsigned short)(u >> 32));
        y[mt * 4 + 3] = bfu2f((unsigned short)(u >> 48));
      } else {                             // new y[32+j] = x1[j]*exp(ls[j]) + shift[j]
        int offx = (m * 128 + 64 + (d0 - 32) * 2) ^ ((m & 7) << 4);
        unsigned long long ux = *reinterpret_cast<const unsigned long long*>(yinb + offx);
        int offs = (m * 64 + (d0 - 32) * 2) ^ ((m & 3) << 4);
        unsigned long long us = *reinterpret_cast<const unsigned long long*>(shfb + offs);
        y[mt * 4 + 0] = bfu2f((unsigned short)(ux)) * __expf(a3[mt][0]) + bfu2f((unsigned short)(us));
        y[mt * 4 + 1] = bfu2f((unsigned short)(ux >> 16)) * __expf(a3[mt][1]) + bfu2f((unsigned short)(us >> 16));
        y[mt * 4 + 2] = bfu2f((unsigned short)(ux >> 32)) * __expf(a3[mt][2]) + bfu2f((unsigned short)(us >> 32));
        y[mt * 4 + 3] = bfu2f((unsigned short)(ux >> 48)) * __expf(a3[mt][3]) + bfu2f((unsigned short)(us >> 48));
      }
    }
    {
      floatx4 mm = *reinterpret_cast<const floatx4*>(bn1m + l * 64 + d0);
      floatx4 vv = *reinterpret_cast<const floatx4*>(bn1v + l * 64 + d0);
      floatx4 gg = *reinterpret_cast<const floatx4*>(bn1g + l * 64 + d0);
      floatx4 be = *reinterpret_cast<const floatx4*>(bn1b + l * 64 + d0);
      float sc[4];
      #pragma unroll
      for (int p = 0; p < 4; ++p) sc[p] = sqrtf(vv[p] + EPSV) / gg[p];
      #pragma unroll
      for (int mt = 0; mt < 2; ++mt)
        #pragma unroll
        for (int p = 0; p < 4; ++p)
          y[mt * 4 + p] = (y[mt * 4 + p] - be[p]) * sc[p] + mm[p];
    }

    for (int i = tid; i < 832; i += 512) { // ODE biases + t-row (b0/b1/t-row PRE-SCALED x2)
      float v;
      if (i < 256)      v = 2.f * ode_b0[l * 256 + i];
      else if (i < 512) v = 2.f * ode_b1[l * 256 + i - 256];
      else if (i < 576) v = ode_b2[l * 64 + i - 512];
      else              v = 2.f * odeW0_full[l * 16640 + i - 576];
      pars[i] = v;
    }
    {                                      // ODE W0 + W1-head + W2 slices -> regs
      const short8* p0 = reinterpret_cast<const short8*>(ws + OW0_OFF + l * 16384);
      const short8* p1 = reinterpret_cast<const short8*>(ws + OW1_OFF + l * 65536);
      const short8* p2 = reinterpret_cast<const short8*>(ws + OW2_OFF + l * 16384);
      #pragma unroll
      for (int nt = 0; nt < 2; ++nt)
        #pragma unroll
        for (int ks = 0; ks < 2; ++ks) aw0[nt][ks] = p0[((w * 2 + nt) * 2 + ks) * 64 + lane];
      #pragma unroll
      for (int nt = 0; nt < 2; ++nt)
        #pragma unroll
        for (int ks = 0; ks < 3; ++ks) aw1h[nt][ks] = p1[((w * 2 + nt) * 8 + ks) * 64 + lane];
      #pragma unroll
      for (int ks = 0; ks < 8; ++ks) aw2[ks] = p2[(wn * 8 + ks) * 64 + lane];
    }
    __syncthreads();                       // B6

    // ================= FFJORD: 8 RK4 steps, 3 barriers/eval =================
    float ka[8], kc[8];
    for (int s = 0; s < NSTEP; ++s) {
      float t0 = (float)s * dtv;
      for (int stg = 0; stg < 4; ++stg) {
        float cadd = (stg == 0) ? 0.0f : ((stg == 3) ? dtv : 0.5f * dtv);
        float tcur = t0 + cadd;
        #pragma unroll
        for (int mt = 0; mt < 2; ++mt) {   // yin = y (+ cadd*k_prev), bf16 [64][64]
          int m = wm * 32 + mt * 16 + l15;
          float v0, v1, v2, v3;
          if (stg == 0) {
            v0 = y[mt * 4 + 0]; v1 = y[mt * 4 + 1]; v2 = y[mt * 4 + 2]; v3 = y[mt * 4 + 3];
          } else {
            v0 = fmaf(cadd, kc[mt * 4 + 0], y[mt * 4 + 0]);
            v1 = fmaf(cadd, kc[mt * 4 + 1], y[mt * 4 + 1]);
            v2 = fmaf(cadd, kc[mt * 4 + 2], y[mt * 4 + 2]);
            v3 = fmaf(cadd, kc[mt * 4 + 3], y[mt * 4 + 3]);
          }
          int off = (m * 128 + d0 * 2) ^ ((m & 7) << 4);
          *reinterpret_cast<unsigned long long*>(yinb + off) = pack4bf(v0, v1, v2, v3);
        }
        __syncthreads();                   // (a)

        // G1: h1 = tanh2(yin @ W0o + b0o + tcur*w0row0), K=64, 2 batches
        #pragma unroll
        for (int mh = 0; mh < 2; ++mh) {
          floatx4 acc[2][2];
          #pragma unroll
          for (int nt = 0; nt < 2; ++nt)
            #pragma unroll
            for (int mt = 0; mt < 2; ++mt) acc[nt][mt] = zero4;
          #pragma unroll
          for (int ks = 0; ks < 2; ++ks) {
            short8 B[2];
            #pragma unroll
            for (int mt = 0; mt < 2; ++mt) {
              int m = mh * 32 + mt * 16 + l15;
              int off = (m * 128 + (ks * 32 + g * 8) * 2) ^ ((m & 7) << 4);
              B[mt] = *reinterpret_cast<const short8*>(yinb + off);
            }
            #pragma unroll
            for (int nt = 0; nt < 2; ++nt)
              #pragma unroll
              for (int mt = 0; mt < 2; ++mt) acc[nt][mt] = MF(aw0[nt][ks], B[mt], acc[nt][mt]);
          }
          #pragma unroll
          for (int nt = 0; nt < 2; ++nt) {
            int nbase = nb + nt * 16 + g * 4;
            floatx4 bb = *reinterpret_cast<const floatx4*>(pars + nbase);
            floatx4 w0 = *reinterpret_cast<const floatx4*>(pars + 576 + nbase);
            float c0 = bb[0] + tcur * w0[0], c1 = bb[1] + tcur * w0[1];
            float c2 = bb[2] + tcur * w0[2], c3 = bb[3] + tcur * w0[3];
            #pragma unroll
            for (int mt = 0; mt < 2; ++mt) {
              int m = mh * 32 + mt * 16 + l15;
              st_h(h1, m, nbase,
                   tanh_fast2(acc[nt][mt][0] + c0), tanh_fast2(acc[nt][mt][1] + c1),
                   tanh_fast2(acc[nt][mt][2] + c2), tanh_fast2(acc[nt][mt][3] + c3));
            }
          }
        }
        __syncthreads();                   // (b)

        // G2: h2 = tanh2(h1 @ W1o + b1o), 2 batches
        #pragma unroll
        for (int mh = 0; mh < 2; ++mh) {
          floatx4 acc[2][2];
          #pragma unroll
          for (int nt = 0; nt < 2; ++nt)
            #pragma unroll
            for (int mt = 0; mt < 2; ++mt) acc[nt][mt] = zero4;
          #pragma unroll
          for (int ks = 0; ks < 8; ++ks) {
            short8 A[2], B[2];
            if (ks < 3) {
              A[0] = aw1h[0][ks]; A[1] = aw1h[1][ks];
            } else {
              A[0] = w1b[((ks - 3) << 10) + (w * 2 + 0) * 64 + lane];
              A[1] = w1b[((ks - 3) << 10) + (w * 2 + 1) * 64 + lane];
            }
            #pragma unroll
            for (int mt = 0; mt < 2; ++mt) {
              int m = mh * 32 + mt * 16 + l15;
              int off = (m * 512 + (ks * 32 + g * 8) * 2) ^ ((m & 15) << 4);
              B[mt] = *reinterpret_cast<const short8*>(h1 + off);
            }
            #pragma unroll
            for (int nt = 0; nt < 2; ++nt)
              #pragma unroll
              for (int mt = 0; mt < 2; ++mt) acc[nt][mt] = MF(A[nt], B[mt], acc[nt][mt]);
          }
          #pragma unroll
          for (int nt = 0; nt < 2; ++nt) {
            int nbase = nb + nt * 16 + g * 4;
            floatx4 bb = *reinterpret_cast<const floatx4*>(pars + 256 + nbase);
            #pragma unroll
            for (int mt = 0; mt < 2; ++mt) {
              int m = mh * 32 + mt * 16 + l15;
              st_h(h2, m, nbase,
                   tanh_fast2(acc[nt][mt][0] + bb[0]), tanh_fast2(acc[nt][mt][1] + bb[1]),
                   tanh_fast2(acc[nt][mt][2] + bb[2]), tanh_fast2(acc[nt][mt][3] + bb[3]));
            }
          }
        }
        __syncthreads();                   // (d')

        // G3: k = h2 @ W2o + b2o (own rows)
        {
          floatx4 a2[2];
          a2[0] = zero4; a2[1] = zero4;
          #pragma unroll
          for (int ks = 0; ks < 8; ++ks) {
            #pragma unroll
            for (int mt = 0; mt < 2; ++mt) {
              int m = wm * 32 + mt * 16 + l15;
              int off = (m * 512 + (ks * 32 + g * 8) * 2) ^ ((m & 15) << 4);
              short8 B = *reinterpret_cast<const short8*>(h2 + off);
              a2[mt] = MF(aw2[ks], B, a2[mt]);
            }
          }
          floatx4 b2v = *reinterpret_cast<const floatx4*>(pars + 512 + d0);
          #pragma unroll
          for (int mt = 0; mt < 2; ++mt)
            #pragma unroll
            for (int p = 0; p < 4; ++p)
              kc[mt * 4 + p] = a2[mt][p] + b2v[p];
        }
        if (stg == 0) {
          #pragma unroll
          for (int i = 0; i < 8; ++i) ka[i] = kc[i];
        } else if (stg == 3) {
          #pragma unroll
          for (int i = 0; i < 8; ++i) ka[i] += kc[i];
        } else {
          #pragma unroll
          for (int i = 0; i < 8; ++i) ka[i] += 2.0f * kc[i];
        }
      }
      #pragma unroll
      for (int i = 0; i < 8; ++i) y[i] += (dtv / 6.0f) * ka[i];
    }

    {                                      // BN2
      floatx4 mm = *reinterpret_cast<const floatx4*>(bn2m + l * 64 + d0);
      floatx4 vv = *reinterpret_cast<const floatx4*>(bn2v + l * 64 + d0);
      floatx4 gg = *reinterpret_cast<const floatx4*>(bn2g + l * 64 + d0);
      floatx4 be = *reinterpret_cast<const floatx4*>(bn2b + l * 64 + d0);
      float sc[4];
      #pragma unroll
      for (int p = 0; p < 4; ++p) sc[p] = sqrtf(vv[p] + EPSV) / gg[p];
      #pragma unroll
      for (int mt = 0; mt < 2; ++mt)
        #pragma unroll
        for (int p = 0; p < 4; ++p)
          y[mt * 4 + p] = (y[mt * 4 + p] - be[p]) * sc[p] + mm[p];
    }
  }

  #pragma unroll
  for (int mt = 0; mt < 2; ++mt) {
    int m = wm * 32 + mt * 16 + l15;
    floatx4 v = {y[mt * 4 + 0], y[mt * 4 + 1], y[mt * 4 + 2], y[mt * 4 + 3]};
    *reinterpret_cast<floatx4*>(out + (row0 + m) * 64 + d0) = v;
  }
}

extern "C" void kernel_launch(void* const* d_in, const int* in_sizes, int n_in,
                              void* d_out, int out_size, void* d_ws, size_t ws_size,
                              hipStream_t stream) {
  const float* x      = (const float*)d_in[0];
  const float* nvpW0  = (const float*)d_in[2];
  const float* nvp_b0 = (const float*)d_in[3];
  const float* nvpW1  = (const float*)d_in[4];
  const float* nvp_b1 = (const float*)d_in[5];
  const float* nvpW2  = (const float*)d_in[6];
  const float* nvp_b2 = (const float*)d_in[7];
  const float* odeW0  = (const float*)d_in[8];
  const float* ode_b0 = (const float*)d_in[9];
  const float* odeW1  = (const float*)d_in[10];
  const float* ode_b1 = (const float*)d_in[11];
  const float* odeW2  = (const float*)d_in[12];
  const float* ode_b2 = (const float*)d_in[13];
  const float* bn1m   = (const float*)d_in[14];
  const float* bn1v   = (const float*)d_in[15];
  const float* bn1g   = (const float*)d_in[16];
  const float* bn1b   = (const float*)d_in[17];
  const float* bn2m   = (const float*)d_in[18];
  const float* bn2v   = (const float*)d_in[19];
  const float* bn2g   = (const float*)d_in[20];
  const float* bn2b   = (const float*)d_in[21];
  unsigned short* ws  = (unsigned short*)d_ws;
  float* out          = (float*)d_out;

  int pblocks = (WS_ELEMS + 255) / 256;
  prep_kernel<<<pblocks, 256, 0, stream>>>(odeW0, odeW1, odeW2, nvpW0, nvpW1, nvpW2, ws);
  flow_kernel<<<512, 512, 0, stream>>>(x, nvp_b0, nvp_b1, nvp_b2, odeW0,
                                       ode_b0, ode_b1, ode_b2,
                                       bn1m, bn1v, bn1g, bn1b,
                                       bn2m, bn2v, bn2g, bn2b,
                                       ws, out);
}

// Round 12
// 1249.207 us; speedup vs baseline: 2.9149x; 1.0029x over previous
//
#include <hip/hip_runtime.h>
#include <hip/hip_bf16.h>

// StackedFlow v11 = v10 - w1b(80KB LDS) + W1-tail-from-L2 => 2 blocks/CU.
// r11: occupancy 23% (159KB LDS -> 1 block/CU, 2 waves/SIMD); barrier drain + latency
// slack ~600us of the 1253us. v11: LDS 75.3KB (h1 32K + h2 32K + yin 8K + pars 3.3K)
// -> 2 co-resident blocks/CU (4 waves/SIMD, independent barriers). W1 ks2..7 A-frags
// read per-eval from d_ws via L2 (24 x 16B loads/wave/eval = 13GB total ~ 376us of
// 34.5TB/s aggregate L2, overlapped; r10/r11 FETCH ~17MB proves ws is L2-resident).
// aw1h shrunk to ks0..1 (16 regs). Canaries: FETCH must stay ~MBs; WRITE <= ~30MB.

#define LNUM   4
#define NSTEP  8
#define EPSV   1e-3f

typedef __attribute__((ext_vector_type(8))) short  short8;
typedef __attribute__((ext_vector_type(4))) float  floatx4;

#define MF(a, b, c) __builtin_amdgcn_mfma_f32_16x16x32_bf16((a), (b), (c), 0, 0, 0)

// d_ws layout (bf16 element offsets), per-GEMM fragment arrays [layer][nt*KS+ks][lane][8]
#define OW0_OFF 0        // ode W0 rows 1..64  (64 x 256)  PRE-SCALED x2
#define OW1_OFF 65536    // ode W1            (256 x 256)  PRE-SCALED x2
#define OW2_OFF 327680   // ode W2            (256 x 64)
#define NW0_OFF 393216   // nvp W0            (32 x 256)
#define NW1_OFF 425984   // nvp W1            (256 x 256)
#define NW2_OFF 688128   // nvp W2            (256 x 64)
#define WS_ELEMS 753664

// LDS byte offsets (64-row tile, 75.3KB -> 2 blocks/CU)
#define H1_OFF   0        // 32K bf16 [64][256] RS=512 swz((m&15)<<4); first 4K aliases shf
#define H2_OFF   32768    // 32K bf16 [64][256] RS=512 swz((m&15)<<4)
#define YIN_OFF  65536    // 8K  bf16 [64][64]  RS=128 swz((m&7)<<4); NVP: x0 lo, x1 hi half-row
#define PARS_OFF 73728    // 3328B: b0 | b1(+256) | b2(+512) | w0row0(+576)
#define LDS_SIZE 77056

__device__ __forceinline__ unsigned short f2bfu_rne(float f) {
  unsigned int u = __float_as_uint(f);
  return (unsigned short)((u + 0x7FFFu + ((u >> 16) & 1u)) >> 16);  // RNE (prep only)
}

__device__ __forceinline__ unsigned long long pack4bf(float a, float b, float c, float d) {
  __hip_bfloat162 lo = __float22bfloat162_rn(make_float2(a, b));
  __hip_bfloat162 hi = __float22bfloat162_rn(make_float2(c, d));
  unsigned int ul, uh;
  __builtin_memcpy(&ul, &lo, 4);
  __builtin_memcpy(&uh, &hi, 4);
  return (unsigned long long)ul | ((unsigned long long)uh << 32);
}

__device__ __forceinline__ float bfu2f(unsigned short u) {
  return __uint_as_float((unsigned int)u << 16);
}

// input v is ALREADY 2x the mathematical pre-activation (weights pre-scaled)
__device__ __forceinline__ float tanh_fast2(float v) {
  float e = __expf(v);
  return 1.0f - 2.0f * __builtin_amdgcn_rcpf(e + 1.0f);
}

// ---------------- weight prep: fp32 [K][N] -> bf16 A-fragment order ----------------
__global__ void prep_kernel(const float* __restrict__ odeW0, const float* __restrict__ odeW1,
                            const float* __restrict__ odeW2, const float* __restrict__ nvpW0,
                            const float* __restrict__ nvpW1, const float* __restrict__ nvpW2,
                            unsigned short* __restrict__ ws) {
  int idx = blockIdx.x * blockDim.x + threadIdx.x;
  if (idx >= WS_ELEMS) return;
  const float* W; int base, K, N, lstride, skip; float scale;
  int f = idx;
  if (f < OW1_OFF)      { W = odeW0; base = OW0_OFF; K = 64;  N = 256; lstride = 16640; skip = 1; scale = 2.f; f -= OW0_OFF; }
  else if (f < OW2_OFF) { W = odeW1; base = OW1_OFF; K = 256; N = 256; lstride = 65536; skip = 0; scale = 2.f; f -= OW1_OFF; }
  else if (f < NW0_OFF) { W = odeW2; base = OW2_OFF; K = 256; N = 64;  lstride = 16384; skip = 0; scale = 1.f; f -= OW2_OFF; }
  else if (f < NW1_OFF) { W = nvpW0; base = NW0_OFF; K = 32;  N = 256; lstride = 8192;  skip = 0; scale = 1.f; f -= NW0_OFF; }
  else if (f < NW2_OFF) { W = nvpW1; base = NW1_OFF; K = 256; N = 256; lstride = 65536; skip = 0; scale = 1.f; f -= NW1_OFF; }
  else                  { W = nvpW2; base = NW2_OFF; K = 256; N = 64;  lstride = 16384; skip = 0; scale = 1.f; f -= NW2_OFF; }
  int per   = K * N;
  int layer = f / per;
  int e     = f - layer * per;
  int j  = e & 7;
  int l  = (e >> 3) & 63;
  int t  = e >> 9;                 // nt*KS + ks
  int KS = K >> 5; if (KS < 1) KS = 1;
  int ks = t % KS;
  int nt = t / KS;
  int n = nt * 16 + (l & 15);
  int k = ks * 32 + ((l >> 4) << 3) + j;
  ws[base + layer * per + e] = f2bfu_rne(scale * W[layer * lstride + (k + skip) * N + n]);
}

// store 4 consecutive n of batch-row m as bf16 into [m][256], swz (m&15)<<4
__device__ __forceinline__ void st_h(char* dst, int m, int n0, float a, float b, float c, float d) {
  int off = (m * 512 + n0 * 2) ^ ((m & 15) << 4);
  *reinterpret_cast<unsigned long long*>(dst + off) = pack4bf(a, b, c, d);
}

// ---------------- fused flow kernel: 512 blocks x 512 threads, 64 rows/block ----------------
__global__ void
__launch_bounds__(512)
flow_kernel(const float* __restrict__ xin,
            const float* __restrict__ nvp_b0, const float* __restrict__ nvp_b1,
            const float* __restrict__ nvp_b2,
            const float* __restrict__ odeW0_full,
            const float* __restrict__ ode_b0, const float* __restrict__ ode_b1,
            const float* __restrict__ ode_b2,
            const float* __restrict__ bn1m, const float* __restrict__ bn1v,
            const float* __restrict__ bn1g, const float* __restrict__ bn1b,
            const float* __restrict__ bn2m, const float* __restrict__ bn2v,
            const float* __restrict__ bn2g, const float* __restrict__ bn2b,
            const unsigned short* __restrict__ ws,
            float* __restrict__ out) {
  __shared__ __align__(16) char smem[LDS_SIZE];
  char*  h1   = smem + H1_OFF;
  char*  h2   = smem + H2_OFF;
  char*  yinb = smem + YIN_OFF;
  char*  shfb = smem + H1_OFF;       // alias: shf [64][32]bf16 in dead h1 space (after B3)
  float* pars = reinterpret_cast<float*>(smem + PARS_OFF);

  const floatx4 zero4 = {0.f, 0.f, 0.f, 0.f};

  const int tid  = threadIdx.x;
  const int lane = tid & 63;
  const int w    = tid >> 6;        // wave 0..7
  const int l15  = lane & 15;
  const int g    = lane >> 4;
  const int wn   = w & 3;           // y/G3 dim-slice (16 of 64)
  const int wm   = w >> 2;          // y/G3 row-half (32 of 64)
  const int nb   = w * 32;          // G1/G2 n-slice base (32 of 256)
  const int row0 = blockIdx.x * 64;
  const int d0   = wn * 16 + g * 4; // this thread's dim base
  const float dtv = 1.0f / NSTEP;

  float y[8];   // y[mt*4+p] at local row (wm*32 + mt*16 + l15), dim (d0+p)
  #pragma unroll
  for (int mt = 0; mt < 2; ++mt) {
    int m = wm * 32 + mt * 16 + l15;
    floatx4 v = *reinterpret_cast<const floatx4*>(xin + (row0 + m) * 64 + d0);
    y[mt * 4 + 0] = v[0]; y[mt * 4 + 1] = v[1]; y[mt * 4 + 2] = v[2]; y[mt * 4 + 3] = v[3];
  }

  short8 aw0[2][2];   // W0 slice: [nt][ks] (NVP: ks=0 only)
  short8 aw1h[2][2];  // W1 slice head: [nt][ks0..1] (regs; ks2..7 from L2 per eval)
  short8 aw2[8];      // W2 slice: n-slice 16 (wn), 8 ks

  for (int l = 0; l < LNUM; ++l) {
    const short8* w1nvp = reinterpret_cast<const short8*>(ws + NW1_OFF + l * 65536);
    const short8* w1ode = reinterpret_cast<const short8*>(ws + OW1_OFF + l * 65536);

    __syncthreads();                       // B0: prev-layer LDS readers done
    #pragma unroll
    for (int mt = 0; mt < 2; ++mt) {       // stash x halves into yin
      int m = wm * 32 + mt * 16 + l15;
      if (wn >= 2) {                       // x0 (dims 32..63) -> low half-row
        int off = (m * 128 + (d0 - 32) * 2) ^ ((m & 7) << 4);
        *reinterpret_cast<unsigned long long*>(yinb + off) =
            pack4bf(y[mt * 4 + 0], y[mt * 4 + 1], y[mt * 4 + 2], y[mt * 4 + 3]);
      } else {                             // x1 (dims 0..31) -> high half-row
        int off = (m * 128 + 64 + d0 * 2) ^ ((m & 7) << 4);
        *reinterpret_cast<unsigned long long*>(yinb + off) =
            pack4bf(y[mt * 4 + 0], y[mt * 4 + 1], y[mt * 4 + 2], y[mt * 4 + 3]);
      }
    }
    for (int i = tid; i < 576; i += 512) { // NVP biases
      float v;
      if (i < 256)      v = nvp_b0[l * 256 + i];
      else if (i < 512) v = nvp_b1[l * 256 + i - 256];
      else              v = nvp_b2[l * 64 + i - 512];
      pars[i] = v;
    }
    {                                      // NVP W0 + W1-head + W2 slices -> regs
      const short8* p0 = reinterpret_cast<const short8*>(ws + NW0_OFF + l * 8192);
      const short8* p2 = reinterpret_cast<const short8*>(ws + NW2_OFF + l * 16384);
      aw0[0][0] = p0[(w * 2 + 0) * 64 + lane];
      aw0[1][0] = p0[(w * 2 + 1) * 64 + lane];
      #pragma unroll
      for (int nt = 0; nt < 2; ++nt)
        #pragma unroll
        for (int ks = 0; ks < 2; ++ks) aw1h[nt][ks] = w1nvp[((w * 2 + nt) * 8 + ks) * 64 + lane];
      #pragma unroll
      for (int ks = 0; ks < 8; ++ks) aw2[ks] = p2[(wn * 8 + ks) * 64 + lane];
    }
    __syncthreads();                       // B1

    // ---- NVP G1: h1 = relu(x0 @ W0n + b0n), K=32, 64 rows in 2 batches ----
    #pragma unroll
    for (int mh = 0; mh < 2; ++mh) {
      floatx4 acc[2][2];
      #pragma unroll
      for (int nt = 0; nt < 2; ++nt)
        #pragma unroll
        for (int mt = 0; mt < 2; ++mt) acc[nt][mt] = zero4;
      short8 B[2];
      #pragma unroll
      for (int mt = 0; mt < 2; ++mt) {
        int m = mh * 32 + mt * 16 + l15;
        int off = (m * 128 + g * 16) ^ ((m & 7) << 4);
        B[mt] = *reinterpret_cast<const short8*>(yinb + off);
      }
      #pragma unroll
      for (int nt = 0; nt < 2; ++nt)
        #pragma unroll
        for (int mt = 0; mt < 2; ++mt) acc[nt][mt] = MF(aw0[nt][0], B[mt], acc[nt][mt]);
      #pragma unroll
      for (int nt = 0; nt < 2; ++nt) {
        int nbase = nb + nt * 16 + g * 4;
        floatx4 bb = *reinterpret_cast<const floatx4*>(pars + nbase);
        #pragma unroll
        for (int mt = 0; mt < 2; ++mt) {
          int m = mh * 32 + mt * 16 + l15;
          st_h(h1, m, nbase,
               fmaxf(acc[nt][mt][0] + bb[0], 0.f), fmaxf(acc[nt][mt][1] + bb[1], 0.f),
               fmaxf(acc[nt][mt][2] + bb[2], 0.f), fmaxf(acc[nt][mt][3] + bb[3], 0.f));
        }
      }
    }
    __syncthreads();                       // B2

    // ---- NVP G2: h2 = relu(h1 @ W1n + b1n), 2 batches (A: regs ks0-1, L2 ks2-7) ----
    #pragma unroll
    for (int mh = 0; mh < 2; ++mh) {
      floatx4 acc[2][2];
      #pragma unroll
      for (int nt = 0; nt < 2; ++nt)
        #pragma unroll
        for (int mt = 0; mt < 2; ++mt) acc[nt][mt] = zero4;
      #pragma unroll
      for (int ks = 0; ks < 8; ++ks) {
        short8 A[2], B[2];
        if (ks < 2) {
          A[0] = aw1h[0][ks]; A[1] = aw1h[1][ks];
        } else {
          A[0] = w1nvp[((w * 2 + 0) * 8 + ks) * 64 + lane];
          A[1] = w1nvp[((w * 2 + 1) * 8 + ks) * 64 + lane];
        }
        #pragma unroll
        for (int mt = 0; mt < 2; ++mt) {
          int m = mh * 32 + mt * 16 + l15;
          int off = (m * 512 + (ks * 32 + g * 8) * 2) ^ ((m & 15) << 4);
          B[mt] = *reinterpret_cast<const short8*>(h1 + off);
        }
        #pragma unroll
        for (int nt = 0; nt < 2; ++nt)
          #pragma unroll
          for (int mt = 0; mt < 2; ++mt) acc[nt][mt] = MF(A[nt], B[mt], acc[nt][mt]);
      }
      #pragma unroll
      for (int nt = 0; nt < 2; ++nt) {
        int nbase = nb + nt * 16 + g * 4;
        floatx4 bb = *reinterpret_cast<const floatx4*>(pars + 256 + nbase);
        #pragma unroll
        for (int mt = 0; mt < 2; ++mt) {
          int m = mh * 32 + mt * 16 + l15;
          st_h(h2, m, nbase,
               fmaxf(acc[nt][mt][0] + bb[0], 0.f), fmaxf(acc[nt][mt][1] + bb[1], 0.f),
               fmaxf(acc[nt][mt][2] + bb[2], 0.f), fmaxf(acc[nt][mt][3] + bb[3], 0.f));
        }
      }
    }
    __syncthreads();                       // B3: G2 h1 reads done, h2 ready

    // ---- NVP G3: a3 = h2 @ W2n + b2n (own rows) ----
    floatx4 a3[2];
    a3[0] = zero4; a3[1] = zero4;
    #pragma unroll
    for (int ks = 0; ks < 8; ++ks) {
      #pragma unroll
      for (int mt = 0; mt < 2; ++mt) {
        int m = wm * 32 + mt * 16 + l15;
        int off = (m * 512 + (ks * 32 + g * 8) * 2) ^ ((m & 15) << 4);
        short8 B = *reinterpret_cast<const short8*>(h2 + off);
        a3[mt] = MF(aw2[ks], B, a3[mt]);
      }
    }
    {
      floatx4 b2v = *reinterpret_cast<const floatx4*>(pars + 512 + d0);
      #pragma unroll
      for (int mt = 0; mt < 2; ++mt)
        #pragma unroll
        for (int p = 0; p < 4; ++p) a3[mt][p] += b2v[p];
    }

    if (wn < 2) {                          // shift (dims 0..31) bf16 -> shf (h1 alias; safe after B3)
      #pragma unroll
      for (int mt = 0; mt < 2; ++mt) {
        int m = wm * 32 + mt * 16 + l15;
        int off = (m * 64 + d0 * 2) ^ ((m & 3) << 4);
        *reinterpret_cast<unsigned long long*>(shfb + off) =
            pack4bf(a3[mt][0], a3[mt][1], a3[mt][2], a3[mt][3]);
      }
    }
    __syncthreads();                       // B5

    // ---- recombine + BN1 ----
    #pragma unroll
    for (int mt = 0; mt < 2; ++mt) {
      int m = wm * 32 + mt * 16 + l15;
      if (wn < 2) {                        // new y[d<32] = x0[d] (pass-through from yin low)
        int off = (m * 128 + d0 * 2) ^ ((m & 7) << 4);
        unsigned long long u = *reinterpret_cast<const unsigned long long*>(yinb + off);
        y[mt * 4 + 0] = bfu2f((unsigned short)(u));
        y[mt * 4 + 1] = bfu2f((unsigned short)(u >> 16));
        y[mt * 4 + 2] = bfu2f((unsigned short)(u >> 32));
        y[mt * 4 + 3] = bfu2f((unsigned short)(u >> 48));
      } else {                             // new y[32+j] = x1[j]*exp(ls[j]) + shift[j]
        int offx = (m * 128 + 64 + (d0 - 32) * 2) ^ ((m & 7) << 4);
        unsigned long long ux = *reinterpret_cast<const unsigned long long*>(yinb + offx);
        int offs = (m * 64 + (d0 - 32) * 2) ^ ((m & 3) << 4);
        unsigned long long us = *reinterpret_cast<const unsigned long long*>(shfb + offs);
        y[mt * 4 + 0] = bfu2f((unsigned short)(ux)) * __expf(a3[mt][0]) + bfu2f((unsigned short)(us));
        y[mt * 4 + 1] = bfu2f((unsigned short)(ux >> 16)) * __expf(a3[mt][1]) + bfu2f((unsigned short)(us >> 16));
        y[mt * 4 + 2] = bfu2f((unsigned short)(ux >> 32)) * __expf(a3[mt][2]) + bfu2f((unsigned short)(us >> 32));
        y[mt * 4 + 3] = bfu2f((unsigned short)(ux >> 48)) * __expf(a3[mt][3]) + bfu2f((unsigned short)(us >> 48));
      }
    }
    {
      floatx4 mm = *reinterpret_cast<const floatx4*>(bn1m + l * 64 + d0);
      floatx4 vv = *reinterpret_cast<const floatx4*>(bn1v + l * 64 + d0);
      floatx4 gg = *reinterpret_cast<const floatx4*>(bn1g + l * 64 + d0);
      floatx4 be = *reinterpret_cast<const floatx4*>(bn1b + l * 64 + d0);
      float sc[4];
      #pragma unroll
      for (int p = 0; p < 4; ++p) sc[p] = sqrtf(vv[p] + EPSV) / gg[p];
      #pragma unroll
      for (int mt = 0; mt < 2; ++mt)
        #pragma unroll
        for (int p = 0; p < 4; ++p)
          y[mt * 4 + p] = (y[mt * 4 + p] - be[p]) * sc[p] + mm[p];
    }

    for (int i = tid; i < 832; i += 512) { // ODE biases + t-row (b0/b1/t-row PRE-SCALED x2)
      float v;
      if (i < 256)      v = 2.f * ode_b0[l * 256 + i];
      else if (i < 512) v = 2.f * ode_b1[l * 256 + i - 256];
      else if (i < 576) v = ode_b2[l * 64 + i - 512];
      else              v = 2.f * odeW0_full[l * 16640 + i - 576];
      pars[i] = v;
    }
    {                                      // ODE W0 + W1-head + W2 slices -> regs
      const short8* p0 = reinterpret_cast<const short8*>(ws + OW0_OFF + l * 16384);
      const short8* p2 = reinterpret_cast<const short8*>(ws + OW2_OFF + l * 16384);
      #pragma unroll
      for (int nt = 0; nt < 2; ++nt)
        #pragma unroll
        for (int ks = 0; ks < 2; ++ks) aw0[nt][ks] = p0[((w * 2 + nt) * 2 + ks) * 64 + lane];
      #pragma unroll
      for (int nt = 0; nt < 2; ++nt)
        #pragma unroll
        for (int ks = 0; ks < 2; ++ks) aw1h[nt][ks] = w1ode[((w * 2 + nt) * 8 + ks) * 64 + lane];
      #pragma unroll
      for (int ks = 0; ks < 8; ++ks) aw2[ks] = p2[(wn * 8 + ks) * 64 + lane];
    }
    __syncthreads();                       // B6

    // ================= FFJORD: 8 RK4 steps, 3 barriers/eval =================
    float ka[8], kc[8];
    for (int s = 0; s < NSTEP; ++s) {
      float t0 = (float)s * dtv;
      for (int stg = 0; stg < 4; ++stg) {
        float cadd = (stg == 0) ? 0.0f : ((stg == 3) ? dtv : 0.5f * dtv);
        float tcur = t0 + cadd;
        #pragma unroll
        for (int mt = 0; mt < 2; ++mt) {   // yin = y (+ cadd*k_prev), bf16 [64][64]
          int m = wm * 32 + mt * 16 + l15;
          float v0, v1, v2, v3;
          if (stg == 0) {
            v0 = y[mt * 4 + 0]; v1 = y[mt * 4 + 1]; v2 = y[mt * 4 + 2]; v3 = y[mt * 4 + 3];
          } else {
            v0 = fmaf(cadd, kc[mt * 4 + 0], y[mt * 4 + 0]);
            v1 = fmaf(cadd, kc[mt * 4 + 1], y[mt * 4 + 1]);
            v2 = fmaf(cadd, kc[mt * 4 + 2], y[mt * 4 + 2]);
            v3 = fmaf(cadd, kc[mt * 4 + 3], y[mt * 4 + 3]);
          }
          int off = (m * 128 + d0 * 2) ^ ((m & 7) << 4);
          *reinterpret_cast<unsigned long long*>(yinb + off) = pack4bf(v0, v1, v2, v3);
        }
        __syncthreads();                   // (a)

        // G1: h1 = tanh2(yin @ W0o + b0o + tcur*w0row0), K=64, 2 batches
        #pragma unroll
        for (int mh = 0; mh < 2; ++mh) {
          floatx4 acc[2][2];
          #pragma unroll
          for (int nt = 0; nt < 2; ++nt)
            #pragma unroll
            for (int mt = 0; mt < 2; ++mt) acc[nt][mt] = zero4;
          #pragma unroll
          for (int ks = 0; ks < 2; ++ks) {
            short8 B[2];
            #pragma unroll
            for (int mt = 0; mt < 2; ++mt) {
              int m = mh * 32 + mt * 16 + l15;
              int off = (m * 128 + (ks * 32 + g * 8) * 2) ^ ((m & 7) << 4);
              B[mt] = *reinterpret_cast<const short8*>(yinb + off);
            }
            #pragma unroll
            for (int nt = 0; nt < 2; ++nt)
              #pragma unroll
              for (int mt = 0; mt < 2; ++mt) acc[nt][mt] = MF(aw0[nt][ks], B[mt], acc[nt][mt]);
          }
          #pragma unroll
          for (int nt = 0; nt < 2; ++nt) {
            int nbase = nb + nt * 16 + g * 4;
            floatx4 bb = *reinterpret_cast<const floatx4*>(pars + nbase);
            floatx4 w0 = *reinterpret_cast<const floatx4*>(pars + 576 + nbase);
            float c0 = bb[0] + tcur * w0[0], c1 = bb[1] + tcur * w0[1];
            float c2 = bb[2] + tcur * w0[2], c3 = bb[3] + tcur * w0[3];
            #pragma unroll
            for (int mt = 0; mt < 2; ++mt) {
              int m = mh * 32 + mt * 16 + l15;
              st_h(h1, m, nbase,
                   tanh_fast2(acc[nt][mt][0] + c0), tanh_fast2(acc[nt][mt][1] + c1),
                   tanh_fast2(acc[nt][mt][2] + c2), tanh_fast2(acc[nt][mt][3] + c3));
            }
          }
        }
        __syncthreads();                   // (b)

        // G2: h2 = tanh2(h1 @ W1o + b1o), 2 batches (A: regs ks0-1, L2 ks2-7)
        #pragma unroll
        for (int mh = 0; mh < 2; ++mh) {
          floatx4 acc[2][2];
          #pragma unroll
          for (int nt = 0; nt < 2; ++nt)
            #pragma unroll
            for (int mt = 0; mt < 2; ++mt) acc[nt][mt] = zero4;
          #pragma unroll
          for (int ks = 0; ks < 8; ++ks) {
            short8 A[2], B[2];
            if (ks < 2) {
              A[0] = aw1h[0][ks]; A[1] = aw1h[1][ks];
            } else {
              A[0] = w1ode[((w * 2 + 0) * 8 + ks) * 64 + lane];
              A[1] = w1ode[((w * 2 + 1) * 8 + ks) * 64 + lane];
            }
            #pragma unroll
            for (int mt = 0; mt < 2; ++mt) {
              int m = mh * 32 + mt * 16 + l15;
              int off = (m * 512 + (ks * 32 + g * 8) * 2) ^ ((m & 15) << 4);
              B[mt] = *reinterpret_cast<const short8*>(h1 + off);
            }
            #pragma unroll
            for (int nt = 0; nt < 2; ++nt)
              #pragma unroll
              for (int mt = 0; mt < 2; ++mt) acc[nt][mt] = MF(A[nt], B[mt], acc[nt][mt]);
          }
          #pragma unroll
          for (int nt = 0; nt < 2; ++nt) {
            int nbase = nb + nt * 16 + g * 4;
            floatx4 bb = *reinterpret_cast<const floatx4*>(pars + 256 + nbase);
            #pragma unroll
            for (int mt = 0; mt < 2; ++mt) {
              int m = mh * 32 + mt * 16 + l15;
              st_h(h2, m, nbase,
                   tanh_fast2(acc[nt][mt][0] + bb[0]), tanh_fast2(acc[nt][mt][1] + bb[1]),
                   tanh_fast2(acc[nt][mt][2] + bb[2]), tanh_fast2(acc[nt][mt][3] + bb[3]));
            }
          }
        }
        __syncthreads();                   // (d')

        // G3: k = h2 @ W2o + b2o (own rows)
        {
          floatx4 a2[2];
          a2[0] = zero4; a2[1] = zero4;
          #pragma unroll
          for (int ks = 0; ks < 8; ++ks) {
            #pragma unroll
            for (int mt = 0; mt < 2; ++mt) {
              int m = wm * 32 + mt * 16 + l15;
              int off = (m * 512 + (ks * 32 + g * 8) * 2) ^ ((m & 15) << 4);
              short8 B = *reinterpret_cast<const short8*>(h2 + off);
              a2[mt] = MF(aw2[ks], B, a2[mt]);
            }
          }
          floatx4 b2v = *reinterpret_cast<const floatx4*>(pars + 512 + d0);
          #pragma unroll
          for (int mt = 0; mt < 2; ++mt)
            #pragma unroll
            for (int p = 0; p < 4; ++p)
              kc[mt * 4 + p] = a2[mt][p] + b2v[p];
        }
        if (stg == 0) {
          #pragma unroll
          for (int i = 0; i < 8; ++i) ka[i] = kc[i];
        } else if (stg == 3) {
          #pragma unroll
          for (int i = 0; i < 8; ++i) ka[i] += kc[i];
        } else {
          #pragma unroll
          for (int i = 0; i < 8; ++i) ka[i] += 2.0f * kc[i];
        }
      }
      #pragma unroll
      for (int i = 0; i < 8; ++i) y[i] += (dtv / 6.0f) * ka[i];
    }

    {                                      // BN2
      floatx4 mm = *reinterpret_cast<const floatx4*>(bn2m + l * 64 + d0);
      floatx4 vv = *reinterpret_cast<const floatx4*>(bn2v + l * 64 + d0);
      floatx4 gg = *reinterpret_cast<const floatx4*>(bn2g + l * 64 + d0);
      floatx4 be = *reinterpret_cast<const floatx4*>(bn2b + l * 64 + d0);
      float sc[4];
      #pragma unroll
      for (int p = 0; p < 4; ++p) sc[p] = sqrtf(vv[p] + EPSV) / gg[p];
      #pragma unroll
      for (int mt = 0; mt < 2; ++mt)
        #pragma unroll
        for (int p = 0; p < 4; ++p)
          y[mt * 4 + p] = (y[mt * 4 + p] - be[p]) * sc[p] + mm[p];
    }
  }

  #pragma unroll
  for (int mt = 0; mt < 2; ++mt) {
    int m = wm * 32 + mt * 16 + l15;
    floatx4 v = {y[mt * 4 + 0], y[mt * 4 + 1], y[mt * 4 + 2], y[mt * 4 + 3]};
    *reinterpret_cast<floatx4*>(out + (row0 + m) * 64 + d0) = v;
  }
}

extern "C" void kernel_launch(void* const* d_in, const int* in_sizes, int n_in,
                              void* d_out, int out_size, void* d_ws, size_t ws_size,
                              hipStream_t stream) {
  const float* x      = (const float*)d_in[0];
  const float* nvpW0  = (const float*)d_in[2];
  const float* nvp_b0 = (const float*)d_in[3];
  const float* nvpW1  = (const float*)d_in[4];
  const float* nvp_b1 = (const float*)d_in[5];
  const float* nvpW2  = (const float*)d_in[6];
  const float* nvp_b2 = (const float*)d_in[7];
  const float* odeW0  = (const float*)d_in[8];
  const float* ode_b0 = (const float*)d_in[9];
  const float* odeW1  = (const float*)d_in[10];
  const float* ode_b1 = (const float*)d_in[11];
  const float* odeW2  = (const float*)d_in[12];
  const float* ode_b2 = (const float*)d_in[13];
  const float* bn1m   = (const float*)d_in[14];
  const float* bn1v   = (const float*)d_in[15];
  const float* bn1g   = (const float*)d_in[16];
  const float* bn1b   = (const float*)d_in[17];
  const float* bn2m   = (const float*)d_in[18];
  const float* bn2v   = (const float*)d_in[19];
  const float* bn2g   = (const float*)d_in[20];
  const float* bn2b   = (const float*)d_in[21];
  unsigned short* ws  = (unsigned short*)d_ws;
  float* out          = (float*)d_out;

  int pblocks = (WS_ELEMS + 255) / 256;
  prep_kernel<<<pblocks, 256, 0, stream>>>(odeW0, odeW1, odeW2, nvpW0, nvpW1, nvpW2, ws);
  flow_kernel<<<512, 512, 0, stream>>>(x, nvp_b0, nvp_b1, nvp_b2, odeW0,
                                       ode_b0, ode_b1, ode_b2,
                                       bn1m, bn1v, bn1g, bn1b,
                                       bn2m, bn2v, bn2g, bn2b,
                                       ws, out);
}